// Round 1
// baseline (1864.151 us; speedup 1.0000x reference)
//
#include <hip/hip_runtime.h>
#include <hip/hip_bf16.h>
#include <math.h>

// Problem constants
#define NB 16
#define LL 2048
#define CC 512
#define HH 8
#define DD 64
#define MM (NB*LL)          // 32768

// ws layout (in floats)
#define OFF_WQT   0u
#define OFF_WKT   262144u
#define OFF_WVT   524288u
#define OFF_WB    786432u          // 1024x512: rows 0..511 Wbig, rows 512..1023 WpT
#define OFF_CVEC  1310720u
#define OFF_GQ    1311232u         // N*H*64 = 8192
#define OFF_PK    1319424u         // N*512  = 8192
#define OFF_Q     1327616u         // 32768*512
#define OFF_KV    18104832u        // 32768*512 (k, then reused as v)
// total 34882048 floats = ~139.5 MB

// ---------------------------------------------------------------------------
// Prep: weight transposes, Wbig = Wt^T folded into Wp, cvec = bp + btfull@Wp^T
// ---------------------------------------------------------------------------
__global__ void prep_kernel(const float* __restrict__ Wq, const float* __restrict__ Wk,
                            const float* __restrict__ Wv, const float* __restrict__ Wt,
                            const float* __restrict__ bt, const float* __restrict__ Wp,
                            const float* __restrict__ bp,
                            float* __restrict__ WqT, float* __restrict__ WkT,
                            float* __restrict__ WvT, float* __restrict__ WB,
                            float* __restrict__ cvec)
{
    const int c = blockIdx.x * 16 + threadIdx.x;   // output col (coalesced writes)
    const int k = blockIdx.y * 16 + threadIdx.y;   // k index
    WqT[k * CC + c] = Wq[c * CC + k];
    WkT[k * CC + c] = Wk[c * CC + k];
    WvT[k * CC + c] = Wv[c * CC + k];
    WB[(512 + k) * CC + c] = Wp[c * CC + k];       // WpT rows
    const int h = k >> 6, d = k & 63;
    float s = 0.f;
    for (int e = 0; e < 64; ++e)
        s += Wt[e * 64 + d] * Wp[c * CC + h * 64 + e];
    WB[k * CC + c] = s;                            // Wbig rows
    if (k == 0) {
        float cv = bp[c];
        for (int j = 0; j < 512; ++j)
            cv += bt[j & 63] * Wp[c * CC + j];
        cvec[c] = cv;
    }
}

// ---------------------------------------------------------------------------
// fp32 GEMM: out[m,n] = sum_k A[m,k]*BT[k,n] + bias[n]
// M=32768, N=512, K=512. 128x128 tile, BK=16, 256 threads, 8x8 micro-tile.
// ---------------------------------------------------------------------------
__global__ __launch_bounds__(256, 2)
void gemm_proj(const float* __restrict__ A, const float* __restrict__ BT,
               const float* __restrict__ bias, float* __restrict__ out)
{
    __shared__ float As[16][132];
    __shared__ float Bs[16][128];
    const int tid = threadIdx.x;
    const int m0 = blockIdx.x * 128;
    const int n0 = blockIdx.y * 128;
    const int tx = tid & 15;
    const int ty = tid >> 4;
    float acc[8][8] = {};

    for (int k0 = 0; k0 < 512; k0 += 16) {
        #pragma unroll
        for (int p = 0; p < 2; ++p) {
            const int f = tid + p * 256;
            const int row = f >> 2;
            const int kq = (f & 3) << 2;
            const float4 v = *(const float4*)&A[(size_t)(m0 + row) * CC + k0 + kq];
            As[kq + 0][row] = v.x; As[kq + 1][row] = v.y;
            As[kq + 2][row] = v.z; As[kq + 3][row] = v.w;
        }
        #pragma unroll
        for (int p = 0; p < 2; ++p) {
            const int f = tid + p * 256;
            const int kk = f >> 5;
            const int nv = (f & 31) << 2;
            *(float4*)&Bs[kk][nv] = *(const float4*)&BT[(size_t)(k0 + kk) * CC + n0 + nv];
        }
        __syncthreads();
        #pragma unroll
        for (int kk = 0; kk < 16; ++kk) {
            const float4 a0 = *(const float4*)&As[kk][tx * 4];
            const float4 a1 = *(const float4*)&As[kk][64 + tx * 4];
            const float4 b0 = *(const float4*)&Bs[kk][ty * 4];
            const float4 b1 = *(const float4*)&Bs[kk][64 + ty * 4];
            const float a[8] = {a0.x, a0.y, a0.z, a0.w, a1.x, a1.y, a1.z, a1.w};
            const float b[8] = {b0.x, b0.y, b0.z, b0.w, b1.x, b1.y, b1.z, b1.w};
            #pragma unroll
            for (int i = 0; i < 8; ++i)
                #pragma unroll
                for (int j = 0; j < 8; ++j)
                    acc[i][j] += a[i] * b[j];
        }
        __syncthreads();
    }

    #pragma unroll
    for (int i = 0; i < 8; ++i) {
        const int rm = (i < 4) ? (tx * 4 + i) : (64 + tx * 4 + i - 4);
        float* orow = out + (size_t)(m0 + rm) * CC + n0;
        #pragma unroll
        for (int jh = 0; jh < 2; ++jh) {
            const int cn = jh * 64 + ty * 4;
            float4 o;
            o.x = acc[i][jh * 4 + 0] + bias[n0 + cn + 0];
            o.y = acc[i][jh * 4 + 1] + bias[n0 + cn + 1];
            o.z = acc[i][jh * 4 + 2] + bias[n0 + cn + 2];
            o.w = acc[i][jh * 4 + 3] + bias[n0 + cn + 3];
            *(float4*)&orow[cn] = o;
        }
    }
}

// ---------------------------------------------------------------------------
// Final GEMM: K=1024 virtual A = [ v * gate | q ], B = [Wbig ; WpT], bias=cvec
// ---------------------------------------------------------------------------
__global__ __launch_bounds__(256, 2)
void gemm_final(const float* __restrict__ V, const float* __restrict__ Q,
                const float* __restrict__ pooled_k, const float* __restrict__ WB,
                const float* __restrict__ cvec, float* __restrict__ out)
{
    __shared__ float As[16][132];
    __shared__ float Bs[16][128];
    __shared__ float gate[512];
    const int tid = threadIdx.x;
    const int m0 = blockIdx.x * 128;
    const int n0 = blockIdx.y * 128;
    const int n = m0 >> 11;                    // sample index (128 | 2048)
    for (int i = tid; i < 512; i += 256) gate[i] = pooled_k[n * 512 + i];
    __syncthreads();
    const int tx = tid & 15;
    const int ty = tid >> 4;
    float acc[8][8] = {};

    for (int k0 = 0; k0 < 1024; k0 += 16) {
        const bool gated = (k0 < 512);
        const float* Asrc = gated ? V : Q;
        const int kb = gated ? k0 : (k0 - 512);
        #pragma unroll
        for (int p = 0; p < 2; ++p) {
            const int f = tid + p * 256;
            const int row = f >> 2;
            const int kq = (f & 3) << 2;
            float4 v = *(const float4*)&Asrc[(size_t)(m0 + row) * CC + kb + kq];
            if (gated) {
                v.x *= gate[k0 + kq + 0]; v.y *= gate[k0 + kq + 1];
                v.z *= gate[k0 + kq + 2]; v.w *= gate[k0 + kq + 3];
            }
            As[kq + 0][row] = v.x; As[kq + 1][row] = v.y;
            As[kq + 2][row] = v.z; As[kq + 3][row] = v.w;
        }
        #pragma unroll
        for (int p = 0; p < 2; ++p) {
            const int f = tid + p * 256;
            const int kk = f >> 5;
            const int nv = (f & 31) << 2;
            *(float4*)&Bs[kk][nv] = *(const float4*)&WB[(size_t)(k0 + kk) * CC + n0 + nv];
        }
        __syncthreads();
        #pragma unroll
        for (int kk = 0; kk < 16; ++kk) {
            const float4 a0 = *(const float4*)&As[kk][tx * 4];
            const float4 a1 = *(const float4*)&As[kk][64 + tx * 4];
            const float4 b0 = *(const float4*)&Bs[kk][ty * 4];
            const float4 b1 = *(const float4*)&Bs[kk][64 + ty * 4];
            const float a[8] = {a0.x, a0.y, a0.z, a0.w, a1.x, a1.y, a1.z, a1.w};
            const float b[8] = {b0.x, b0.y, b0.z, b0.w, b1.x, b1.y, b1.z, b1.w};
            #pragma unroll
            for (int i = 0; i < 8; ++i)
                #pragma unroll
                for (int j = 0; j < 8; ++j)
                    acc[i][j] += a[i] * b[j];
        }
        __syncthreads();
    }

    #pragma unroll
    for (int i = 0; i < 8; ++i) {
        const int rm = (i < 4) ? (tx * 4 + i) : (64 + tx * 4 + i - 4);
        float* orow = out + (size_t)(m0 + rm) * CC + n0;
        #pragma unroll
        for (int jh = 0; jh < 2; ++jh) {
            const int cn = jh * 64 + ty * 4;
            float4 o;
            o.x = acc[i][jh * 4 + 0] + cvec[n0 + cn + 0];
            o.y = acc[i][jh * 4 + 1] + cvec[n0 + cn + 1];
            o.z = acc[i][jh * 4 + 2] + cvec[n0 + cn + 2];
            o.w = acc[i][jh * 4 + 3] + cvec[n0 + cn + 3];
            *(float4*)&orow[cn] = o;
        }
    }
}

// ---------------------------------------------------------------------------
// Additive pooling: per (n,h) block. score_l = (dot(src[l,:], wv) + b)/8,
// softmax over L, pooled[d] = sum_l w_l * src[l,d] (* postmul).
// modeK: wv comes from gq[nh*64]; else wv = wqa (shared).
// ---------------------------------------------------------------------------
__global__ __launch_bounds__(256)
void pool_kernel(const float* __restrict__ src, const float* __restrict__ wvec,
                 const float* __restrict__ bscal, const float* __restrict__ postmul,
                 float* __restrict__ pooled_out, int modeK)
{
    __shared__ float sc[2048];
    __shared__ float red[16];
    const int nh = blockIdx.x;
    const int n = nh >> 3, h = nh & 7;
    const int tid = threadIdx.x;
    const int wave = tid >> 6, lane = tid & 63;
    const float* wv = modeK ? (wvec + nh * 64) : wvec;
    const float w_d = wv[lane];
    const float b = bscal[0];
    const float isd = 0.125f;    // 1/sqrt(64)
    const float* base = src + (size_t)n * LL * CC + h * 64;

    // phase 1: scores
    for (int l = wave; l < LL; l += 4) {
        float s = base[(size_t)l * CC + lane] * w_d;
        #pragma unroll
        for (int off = 32; off > 0; off >>= 1) s += __shfl_down(s, off, 64);
        if (lane == 0) sc[l] = (s + b) * isd;
    }
    __syncthreads();

    // phase 2: softmax (max, exp, sum)
    float mx = -INFINITY;
    for (int i = tid; i < LL; i += 256) mx = fmaxf(mx, sc[i]);
    #pragma unroll
    for (int off = 32; off > 0; off >>= 1) mx = fmaxf(mx, __shfl_down(mx, off, 64));
    if (lane == 0) red[wave] = mx;
    __syncthreads();
    mx = fmaxf(fmaxf(red[0], red[1]), fmaxf(red[2], red[3]));
    float sum = 0.f;
    for (int i = tid; i < LL; i += 256) {
        const float e = expf(sc[i] - mx);
        sc[i] = e;
        sum += e;
    }
    #pragma unroll
    for (int off = 32; off > 0; off >>= 1) sum += __shfl_down(sum, off, 64);
    if (lane == 0) red[8 + wave] = sum;
    __syncthreads();
    const float S = red[8] + red[9] + red[10] + red[11];

    // phase 3: weighted sum over L
    float acc = 0.f;
    for (int l = wave; l < LL; l += 4)
        acc += sc[l] * base[(size_t)l * CC + lane];
    __syncthreads();                 // everyone done reading sc
    sc[wave * 64 + lane] = acc;
    __syncthreads();
    if (wave == 0) {
        float p = sc[lane] + sc[64 + lane] + sc[128 + lane] + sc[192 + lane];
        p /= S;
        if (postmul) p *= postmul[lane];
        pooled_out[nh * 64 + lane] = p;
    }
}

// ---------------------------------------------------------------------------
extern "C" void kernel_launch(void* const* d_in, const int* in_sizes, int n_in,
                              void* d_out, int out_size, void* d_ws, size_t ws_size,
                              hipStream_t stream) {
    const float* x_q  = (const float*)d_in[0];
    const float* x_kv = (const float*)d_in[1];
    const float* Wq   = (const float*)d_in[2];
    const float* bq   = (const float*)d_in[3];
    const float* wqa  = (const float*)d_in[4];
    const float* bqa  = (const float*)d_in[5];
    const float* Wk   = (const float*)d_in[6];
    const float* bk   = (const float*)d_in[7];
    const float* wka  = (const float*)d_in[8];
    const float* bka  = (const float*)d_in[9];
    const float* Wv   = (const float*)d_in[10];
    const float* bv   = (const float*)d_in[11];
    const float* Wt   = (const float*)d_in[12];
    const float* bt   = (const float*)d_in[13];
    const float* Wp   = (const float*)d_in[14];
    const float* bp   = (const float*)d_in[15];
    float* out = (float*)d_out;
    float* ws = (float*)d_ws;

    float* WqT  = ws + OFF_WQT;
    float* WkT  = ws + OFF_WKT;
    float* WvT  = ws + OFF_WVT;
    float* WB   = ws + OFF_WB;
    float* cvec = ws + OFF_CVEC;
    float* gq   = ws + OFF_GQ;
    float* pk   = ws + OFF_PK;
    float* qbuf = ws + OFF_Q;
    float* kvbuf= ws + OFF_KV;

    // 1. weight prep
    prep_kernel<<<dim3(32, 32), dim3(16, 16), 0, stream>>>(
        Wq, Wk, Wv, Wt, bt, Wp, bp, WqT, WkT, WvT, WB, cvec);

    const dim3 ggrid(MM / 128, CC / 128);

    // 2. q projection
    gemm_proj<<<ggrid, 256, 0, stream>>>(x_q, WqT, bq, qbuf);
    // 3. q pooling -> gq = pooled_q * wka
    pool_kernel<<<NB * HH, 256, 0, stream>>>(qbuf, wqa, bqa, wka, gq, 0);
    // 4. k projection
    gemm_proj<<<ggrid, 256, 0, stream>>>(x_kv, WkT, bk, kvbuf);
    // 5. k pooling -> pooled_k
    pool_kernel<<<NB * HH, 256, 0, stream>>>(kvbuf, gq, bka, nullptr, pk, 1);
    // 6. v projection (reuse kv buffer)
    gemm_proj<<<ggrid, 256, 0, stream>>>(x_kv, WvT, bv, kvbuf);
    // 7. fused (v*pk)@Wbig + q@WpT + cvec
    gemm_final<<<ggrid, 256, 0, stream>>>(kvbuf, qbuf, pk, WB, cvec, out);
}

// Round 2
// 1324.580 us; speedup vs baseline: 1.4074x; 1.4074x over previous
//
#include <hip/hip_runtime.h>
#include <hip/hip_bf16.h>
#include <math.h>

// Problem constants
#define NB 16
#define LL 2048
#define CC 512
#define HH 8
#define MM (NB*LL)          // 32768

typedef __attribute__((ext_vector_type(8))) short bf16x8;
typedef __attribute__((ext_vector_type(4))) float f32x4;
typedef __attribute__((ext_vector_type(8))) unsigned short u16x8;

// ---------------------------------------------------------------------------
// bf16 split helpers: x ≈ hi + lo, both bf16. Missing term lo*lo ~ 2^-18 rel.
// ---------------------------------------------------------------------------
__device__ inline unsigned short f2bf(float x) {
    __hip_bfloat16 b = __float2bfloat16(x);
    return __builtin_bit_cast(unsigned short, b);
}
__device__ inline float bf2f(unsigned short u) {
    __hip_bfloat16 b = __builtin_bit_cast(__hip_bfloat16, u);
    return __bfloat162float(b);
}
__device__ inline void split2(float x, unsigned short& h, unsigned short& l) {
    unsigned short hh = f2bf(x);
    float fh = bf2f(hh);
    h = hh;
    l = f2bf(x - fh);
}

// ---------------------------------------------------------------------------
// Prep: pack proj weights (hi/lo, fragment-packed) + fold Wt into Wp -> WB,
// cvec = bp + (bt broadcast) @ Wp^T.
// B-packed layout: [nt][kp][n%128][k%8], value = W[n][k] (y = x @ W^T).
// ---------------------------------------------------------------------------
__global__ __launch_bounds__(256)
void prep_kernel(const float* __restrict__ Wq, const float* __restrict__ Wk,
                 const float* __restrict__ Wv, const float* __restrict__ Wt,
                 const float* __restrict__ bt, const float* __restrict__ Wp,
                 const float* __restrict__ bp,
                 unsigned short* __restrict__ Bqh, unsigned short* __restrict__ Bql,
                 unsigned short* __restrict__ Bkh, unsigned short* __restrict__ Bkl,
                 unsigned short* __restrict__ Bvh, unsigned short* __restrict__ Bvl,
                 unsigned short* __restrict__ WBh, unsigned short* __restrict__ WBl,
                 float* __restrict__ cvec)
{
    const int t = blockIdx.x * 256 + threadIdx.x;   // 512*1024 threads
    const int c = t >> 10;         // output col n, 0..511
    const int k = t & 1023;        // virtual K, 0..1023
    float val;
    if (k < 512) {   // Wbig[k=h*64+d][c] = sum_e Wt[e][d] * Wp[c][h*64+e]
        const int h = k >> 6, d = k & 63;
        float s = 0.f;
        #pragma unroll 8
        for (int e = 0; e < 64; ++e) s += Wt[e * 64 + d] * Wp[c * CC + h * 64 + e];
        val = s;
    } else {         // WpT rows
        val = Wp[c * CC + (k - 512)];
    }
    unsigned short hh, ll;
    split2(val, hh, ll);
    const size_t pw = (((size_t)(c >> 7) * 128 + (k >> 3)) * 128 + (c & 127)) * 8 + (k & 7);
    WBh[pw] = hh; WBl[pw] = ll;
    if (k < 512) {
        const size_t pq = (((size_t)(c >> 7) * 64 + (k >> 3)) * 128 + (c & 127)) * 8 + (k & 7);
        split2(Wq[c * CC + k], hh, ll); Bqh[pq] = hh; Bql[pq] = ll;
        split2(Wk[c * CC + k], hh, ll); Bkh[pq] = hh; Bkl[pq] = ll;
        split2(Wv[c * CC + k], hh, ll); Bvh[pq] = hh; Bvl[pq] = ll;
    }
    if (k == 0) {
        float cv = bp[c];
        for (int j = 0; j < 512; ++j) cv += bt[j & 63] * Wp[c * CC + j];
        cvec[c] = cv;
    }
}

// ---------------------------------------------------------------------------
// Convert fp32 [M][512] (optionally * per-sample gate[n][512]) into hi/lo bf16
// fragment-packed [mt][kp][m%128][k%8].
// ---------------------------------------------------------------------------
__global__ __launch_bounds__(256)
void convert_pack(const float* __restrict__ src, const float* __restrict__ gate,
                  unsigned short* __restrict__ oh, unsigned short* __restrict__ ol)
{
    const int mt = blockIdx.x;       // 0..255
    const int m0 = mt * 128;
    const int n = mt >> 4;           // sample (128 rows | 2048-row samples)
    for (int it = 0; it < 32; ++it) {
        const int q = it * 256 + threadIdx.x;   // 8192 = 128 rows * 64 panels
        const int kp = q & 63, row = q >> 6;
        const float* s = src + (size_t)(m0 + row) * CC + kp * 8;
        float x[8];
        *(float4*)&x[0] = *(const float4*)s;
        *(float4*)&x[4] = *(const float4*)(s + 4);
        if (gate != nullptr) {
            const float* g = gate + n * CC + kp * 8;
            float gg[8];
            *(float4*)&gg[0] = *(const float4*)g;
            *(float4*)&gg[4] = *(const float4*)(g + 4);
            #pragma unroll
            for (int j = 0; j < 8; ++j) x[j] *= gg[j];
        }
        u16x8 hv, lv;
        #pragma unroll
        for (int j = 0; j < 8; ++j) {
            unsigned short h, lo;
            split2(x[j], h, lo);
            hv[j] = h; lv[j] = lo;
        }
        const size_t o = (((size_t)mt * 64 + kp) * 128 + row) * 8;
        *(u16x8*)&oh[o] = hv;
        *(u16x8*)&ol[o] = lv;
    }
}

// ---------------------------------------------------------------------------
// bf16 split-3 MFMA GEMM.  out[m,n] = sum_k A[m,k]*W[n,k] + bias[n], fp32 out.
// A virtual-K = concat(A1 [KT1 ktiles], A2 [KT2 ktiles]); ktile = 32 k.
// 128x128 tile, 4 waves (2x2), 4x4 fragments of 16x16x32, 48 MFMA/wave/ktile.
// Packed tiles: contiguous 8KB per (tile, ktile); LDS layout == global layout.
// ---------------------------------------------------------------------------
template<int KT1, int KT2>
__global__ __launch_bounds__(256)
void gemm_bf16s(const unsigned short* __restrict__ A1h, const unsigned short* __restrict__ A1l,
                const unsigned short* __restrict__ A2h, const unsigned short* __restrict__ A2l,
                const unsigned short* __restrict__ Bh,  const unsigned short* __restrict__ Bl,
                const float* __restrict__ bias, float* __restrict__ out)
{
    constexpr int KT = KT1 + KT2;
    __shared__ __align__(16) unsigned short sAh[4096], sAl[4096], sBh[4096], sBl[4096];
    const int tid = threadIdx.x;
    const int nt = blockIdx.x;            // 0..3
    const int mt = blockIdx.y;            // 0..255
    const int n0 = nt * 128, m0 = mt * 128;
    const int l = tid & 63, w = tid >> 6;
    const int wm = w >> 1, wn = w & 1;
    const int so = w * 1024 + (l << 4);   // staging byte offset (wave chunk + lane*16)

    f32x4 acc[4][4] = {};

    uint4 rAh0, rAh1, rAl0, rAl1, rBh0, rBh1, rBl0, rBl1;
    auto loadTile = [&](int kt) {
        const char *ah, *al;
        if (KT2 == 0 || kt < KT1) {
            const size_t o = ((size_t)mt * KT1 + kt) * 8192;
            ah = (const char*)A1h + o; al = (const char*)A1l + o;
        } else {
            const size_t o = ((size_t)mt * KT2 + (kt - KT1)) * 8192;
            ah = (const char*)A2h + o; al = (const char*)A2l + o;
        }
        const size_t ob = ((size_t)nt * KT + kt) * 8192;
        const char* bh = (const char*)Bh + ob;
        const char* bl = (const char*)Bl + ob;
        rAh0 = *(const uint4*)(ah + so); rAh1 = *(const uint4*)(ah + so + 4096);
        rAl0 = *(const uint4*)(al + so); rAl1 = *(const uint4*)(al + so + 4096);
        rBh0 = *(const uint4*)(bh + so); rBh1 = *(const uint4*)(bh + so + 4096);
        rBl0 = *(const uint4*)(bl + so); rBl1 = *(const uint4*)(bl + so + 4096);
    };
    loadTile(0);

    for (int kt = 0; kt < KT; ++kt) {
        __syncthreads();   // prior iteration's LDS reads complete
        *(uint4*)((char*)sAh + so) = rAh0; *(uint4*)((char*)sAh + so + 4096) = rAh1;
        *(uint4*)((char*)sAl + so) = rAl0; *(uint4*)((char*)sAl + so + 4096) = rAl1;
        *(uint4*)((char*)sBh + so) = rBh0; *(uint4*)((char*)sBh + so + 4096) = rBh1;
        *(uint4*)((char*)sBl + so) = rBl0; *(uint4*)((char*)sBl + so + 4096) = rBl1;
        __syncthreads();   // LDS ready
        if (kt + 1 < KT) loadTile(kt + 1);   // prefetch overlaps MFMAs

        const int g = l >> 4;
        const int rA = wm * 64 + (l & 15);
        const int rB = wn * 64 + (l & 15);
        const bf16x8* vAh = (const bf16x8*)sAh; const bf16x8* vAl = (const bf16x8*)sAl;
        const bf16x8* vBh = (const bf16x8*)sBh; const bf16x8* vBl = (const bf16x8*)sBl;
        bf16x8 ah[4], al[4], bh[4], bl[4];
        #pragma unroll
        for (int f = 0; f < 4; ++f) {
            ah[f] = vAh[g * 128 + rA + f * 16];
            al[f] = vAl[g * 128 + rA + f * 16];
            bh[f] = vBh[g * 128 + rB + f * 16];
            bl[f] = vBl[g * 128 + rB + f * 16];
        }
        #pragma unroll
        for (int i = 0; i < 4; ++i)
            #pragma unroll
            for (int j = 0; j < 4; ++j) {
                acc[i][j] = __builtin_amdgcn_mfma_f32_16x16x32_bf16(ah[i], bh[j], acc[i][j], 0, 0, 0);
                acc[i][j] = __builtin_amdgcn_mfma_f32_16x16x32_bf16(ah[i], bl[j], acc[i][j], 0, 0, 0);
                acc[i][j] = __builtin_amdgcn_mfma_f32_16x16x32_bf16(al[i], bh[j], acc[i][j], 0, 0, 0);
            }
    }

    // epilogue: C/D layout col = lane&15, row = (lane>>4)*4 + reg  [m89/m91]
    const int rowb = (l >> 4) * 4, colb = l & 15;
    #pragma unroll
    for (int j = 0; j < 4; ++j) {
        const int c = n0 + wn * 64 + j * 16 + colb;
        const float bv = bias[c];
        #pragma unroll
        for (int i = 0; i < 4; ++i) {
            const int r = m0 + wm * 64 + i * 16 + rowb;
            #pragma unroll
            for (int e = 0; e < 4; ++e)
                out[(size_t)(r + e) * CC + c] = acc[i][j][e] + bv;
        }
    }
}

// ---------------------------------------------------------------------------
// Additive pooling (unchanged, verified round 1): per (n,h) block.
// ---------------------------------------------------------------------------
__global__ __launch_bounds__(256)
void pool_kernel(const float* __restrict__ src, const float* __restrict__ wvec,
                 const float* __restrict__ bscal, const float* __restrict__ postmul,
                 float* __restrict__ pooled_out, int modeK)
{
    __shared__ float sc[2048];
    __shared__ float red[16];
    const int nh = blockIdx.x;
    const int n = nh >> 3, h = nh & 7;
    const int tid = threadIdx.x;
    const int wave = tid >> 6, lane = tid & 63;
    const float* wv = modeK ? (wvec + nh * 64) : wvec;
    const float w_d = wv[lane];
    const float b = bscal[0];
    const float isd = 0.125f;
    const float* base = src + (size_t)n * LL * CC + h * 64;

    for (int l = wave; l < LL; l += 4) {
        float s = base[(size_t)l * CC + lane] * w_d;
        #pragma unroll
        for (int off = 32; off > 0; off >>= 1) s += __shfl_down(s, off, 64);
        if (lane == 0) sc[l] = (s + b) * isd;
    }
    __syncthreads();

    float mx = -INFINITY;
    for (int i = tid; i < LL; i += 256) mx = fmaxf(mx, sc[i]);
    #pragma unroll
    for (int off = 32; off > 0; off >>= 1) mx = fmaxf(mx, __shfl_down(mx, off, 64));
    if (lane == 0) red[wave] = mx;
    __syncthreads();
    mx = fmaxf(fmaxf(red[0], red[1]), fmaxf(red[2], red[3]));
    float sum = 0.f;
    for (int i = tid; i < LL; i += 256) {
        const float e = expf(sc[i] - mx);
        sc[i] = e;
        sum += e;
    }
    #pragma unroll
    for (int off = 32; off > 0; off >>= 1) sum += __shfl_down(sum, off, 64);
    if (lane == 0) red[8 + wave] = sum;
    __syncthreads();
    const float S = red[8] + red[9] + red[10] + red[11];

    float acc = 0.f;
    for (int l = wave; l < LL; l += 4)
        acc += sc[l] * base[(size_t)l * CC + lane];
    __syncthreads();
    sc[wave * 64 + lane] = acc;
    __syncthreads();
    if (wave == 0) {
        float p = sc[lane] + sc[64 + lane] + sc[128 + lane] + sc[192 + lane];
        p /= S;
        if (postmul) p *= postmul[lane];
        pooled_out[nh * 64 + lane] = p;
    }
}

// ---------------------------------------------------------------------------
// ws byte offsets (~198 MB total)
// ---------------------------------------------------------------------------
#define OFF_BQH   0ull
#define OFF_BQL   524288ull
#define OFF_BKH   1048576ull
#define OFF_BKL   1572864ull
#define OFF_BVH   2097152ull
#define OFF_BVL   2621440ull
#define OFF_WBH   3145728ull
#define OFF_WBL   4194304ull
#define OFF_CVEC  5242880ull
#define OFF_GQ    5259264ull
#define OFF_PK    5292032ull
#define OFF_APKH  6291456ull       // 32MB: Aq_hi -> Akv_hi -> Vg_hi
#define OFF_APKL  39845888ull      // 32MB: lo
#define OFF_QBUF  73400320ull      // 64MB fp32 q
#define OFF_KV    140509184ull     // 64MB fp32 k/v, later Qp_hi+Qp_lo
#define OFF_QPH   140509184ull
#define OFF_QPL   174063616ull

extern "C" void kernel_launch(void* const* d_in, const int* in_sizes, int n_in,
                              void* d_out, int out_size, void* d_ws, size_t ws_size,
                              hipStream_t stream) {
    const float* x_q  = (const float*)d_in[0];
    const float* x_kv = (const float*)d_in[1];
    const float* Wq   = (const float*)d_in[2];
    const float* bq   = (const float*)d_in[3];
    const float* wqa  = (const float*)d_in[4];
    const float* bqa  = (const float*)d_in[5];
    const float* Wk   = (const float*)d_in[6];
    const float* bk   = (const float*)d_in[7];
    const float* wka  = (const float*)d_in[8];
    const float* bka  = (const float*)d_in[9];
    const float* Wv   = (const float*)d_in[10];
    const float* bv   = (const float*)d_in[11];
    const float* Wt   = (const float*)d_in[12];
    const float* bt   = (const float*)d_in[13];
    const float* Wp   = (const float*)d_in[14];
    const float* bp   = (const float*)d_in[15];
    float* out = (float*)d_out;
    char* ws = (char*)d_ws;

    unsigned short* Bqh = (unsigned short*)(ws + OFF_BQH);
    unsigned short* Bql = (unsigned short*)(ws + OFF_BQL);
    unsigned short* Bkh = (unsigned short*)(ws + OFF_BKH);
    unsigned short* Bkl = (unsigned short*)(ws + OFF_BKL);
    unsigned short* Bvh = (unsigned short*)(ws + OFF_BVH);
    unsigned short* Bvl = (unsigned short*)(ws + OFF_BVL);
    unsigned short* WBh = (unsigned short*)(ws + OFF_WBH);
    unsigned short* WBl = (unsigned short*)(ws + OFF_WBL);
    float* cvec = (float*)(ws + OFF_CVEC);
    float* gq   = (float*)(ws + OFF_GQ);
    float* pk   = (float*)(ws + OFF_PK);
    unsigned short* APh = (unsigned short*)(ws + OFF_APKH);
    unsigned short* APl = (unsigned short*)(ws + OFF_APKL);
    float* qbuf  = (float*)(ws + OFF_QBUF);
    float* kvbuf = (float*)(ws + OFF_KV);
    unsigned short* QPh = (unsigned short*)(ws + OFF_QPH);
    unsigned short* QPl = (unsigned short*)(ws + OFF_QPL);

    const dim3 ggrid(4, 256);

    // 1. weight prep (packed hi/lo + Wt-fold + cvec)
    prep_kernel<<<2048, 256, 0, stream>>>(Wq, Wk, Wv, Wt, bt, Wp, bp,
                                          Bqh, Bql, Bkh, Bkl, Bvh, Bvl, WBh, WBl, cvec);
    // 2. pack x_q
    convert_pack<<<256, 256, 0, stream>>>(x_q, nullptr, APh, APl);
    // 3. q projection (MFMA)
    gemm_bf16s<16, 0><<<ggrid, 256, 0, stream>>>(APh, APl, nullptr, nullptr, Bqh, Bql, bq, qbuf);
    // 4. q pooling -> gq = pooled_q * wka
    pool_kernel<<<NB * HH, 256, 0, stream>>>(qbuf, wqa, bqa, wka, gq, 0);
    // 5. pack x_kv (over x_q packing)
    convert_pack<<<256, 256, 0, stream>>>(x_kv, nullptr, APh, APl);
    // 6. k projection
    gemm_bf16s<16, 0><<<ggrid, 256, 0, stream>>>(APh, APl, nullptr, nullptr, Bkh, Bkl, bk, kvbuf);
    // 7. k pooling -> pooled_k [16][512]
    pool_kernel<<<NB * HH, 256, 0, stream>>>(kvbuf, gq, bka, nullptr, pk, 1);
    // 8. v projection (same packed x_kv; overwrite kvbuf with v)
    gemm_bf16s<16, 0><<<ggrid, 256, 0, stream>>>(APh, APl, nullptr, nullptr, Bvh, Bvl, bv, kvbuf);
    // 9. pack v * pooled_k (over x_kv packing)
    convert_pack<<<256, 256, 0, stream>>>(kvbuf, pk, APh, APl);
    // 10. pack q (over kvbuf)
    convert_pack<<<256, 256, 0, stream>>>(qbuf, nullptr, QPh, QPl);
    // 11. fused final: (v*pk)@Wbig + q@WpT + cvec
    gemm_bf16s<16, 16><<<ggrid, 256, 0, stream>>>(APh, APl, QPh, QPl, WBh, WBl, cvec, out);
}

// Round 3
// 701.453 us; speedup vs baseline: 2.6576x; 1.8883x over previous
//
#include <hip/hip_runtime.h>
#include <hip/hip_bf16.h>
#include <math.h>

// Problem constants
#define NB 16
#define LL 2048
#define CC 512
#define HH 8
#define MM (NB*LL)          // 32768

typedef __attribute__((ext_vector_type(8))) short bf16x8;
typedef __attribute__((ext_vector_type(4))) float f32x4;
typedef __attribute__((ext_vector_type(8))) unsigned short u16x8;

// ---------------------------------------------------------------------------
// bf16 split helpers: x ≈ hi + lo, both bf16. Missing term lo*lo ~ 2^-18 rel.
// ---------------------------------------------------------------------------
__device__ inline unsigned short f2bf(float x) {
    __hip_bfloat16 b = __float2bfloat16(x);
    return __builtin_bit_cast(unsigned short, b);
}
__device__ inline float bf2f(unsigned short u) {
    __hip_bfloat16 b = __builtin_bit_cast(__hip_bfloat16, u);
    return __bfloat162float(b);
}
__device__ inline void split2(float x, unsigned short& h, unsigned short& l) {
    unsigned short hh = f2bf(x);
    float fh = bf2f(hh);
    h = hh;
    l = f2bf(x - fh);
}

// ---------------------------------------------------------------------------
// Prep: pack proj weights (hi/lo, fragment-packed) + fold Wt into Wp -> WB,
// cvec = bp + (bt broadcast) @ Wp^T.
// ---------------------------------------------------------------------------
__global__ __launch_bounds__(256)
void prep_kernel(const float* __restrict__ Wq, const float* __restrict__ Wk,
                 const float* __restrict__ Wv, const float* __restrict__ Wt,
                 const float* __restrict__ bt, const float* __restrict__ Wp,
                 const float* __restrict__ bp,
                 unsigned short* __restrict__ Bqh, unsigned short* __restrict__ Bql,
                 unsigned short* __restrict__ Bkh, unsigned short* __restrict__ Bkl,
                 unsigned short* __restrict__ Bvh, unsigned short* __restrict__ Bvl,
                 unsigned short* __restrict__ WBh, unsigned short* __restrict__ WBl,
                 float* __restrict__ cvec)
{
    const int t = blockIdx.x * 256 + threadIdx.x;   // 512*1024 threads
    const int c = t >> 10;         // output col n, 0..511
    const int k = t & 1023;        // virtual K, 0..1023
    float val;
    if (k < 512) {   // Wbig[k=h*64+d][c] = sum_e Wt[e][d] * Wp[c][h*64+e]
        const int h = k >> 6, d = k & 63;
        float s = 0.f;
        #pragma unroll 8
        for (int e = 0; e < 64; ++e) s += Wt[e * 64 + d] * Wp[c * CC + h * 64 + e];
        val = s;
    } else {         // WpT rows
        val = Wp[c * CC + (k - 512)];
    }
    unsigned short hh, ll;
    split2(val, hh, ll);
    const size_t pw = (((size_t)(c >> 7) * 128 + (k >> 3)) * 128 + (c & 127)) * 8 + (k & 7);
    WBh[pw] = hh; WBl[pw] = ll;
    if (k < 512) {
        const size_t pq = (((size_t)(c >> 7) * 64 + (k >> 3)) * 128 + (c & 127)) * 8 + (k & 7);
        split2(Wq[c * CC + k], hh, ll); Bqh[pq] = hh; Bql[pq] = ll;
        split2(Wk[c * CC + k], hh, ll); Bkh[pq] = hh; Bkl[pq] = ll;
        split2(Wv[c * CC + k], hh, ll); Bvh[pq] = hh; Bvl[pq] = ll;
    }
    if (k == 0) {
        float cv = bp[c];
        for (int j = 0; j < 512; ++j) cv += bt[j & 63] * Wp[c * CC + j];
        cvec[c] = cv;
    }
}

// ---------------------------------------------------------------------------
// Convert fp32 [M][512] (optionally * per-sample gate[n][512]) into hi/lo bf16
// fragment-packed [mt][kp][m%128][k%8].
// ---------------------------------------------------------------------------
__global__ __launch_bounds__(256)
void convert_pack(const float* __restrict__ src, const float* __restrict__ gate,
                  unsigned short* __restrict__ oh, unsigned short* __restrict__ ol)
{
    const int mt = blockIdx.x;       // 0..255
    const int m0 = mt * 128;
    const int n = mt >> 4;           // sample (128 rows | 2048-row samples)
    for (int it = 0; it < 32; ++it) {
        const int q = it * 256 + threadIdx.x;   // 8192 = 128 rows * 64 panels
        const int kp = q & 63, row = q >> 6;
        const float* s = src + (size_t)(m0 + row) * CC + kp * 8;
        float x[8];
        *(float4*)&x[0] = *(const float4*)s;
        *(float4*)&x[4] = *(const float4*)(s + 4);
        if (gate != nullptr) {
            const float* g = gate + n * CC + kp * 8;
            float gg[8];
            *(float4*)&gg[0] = *(const float4*)g;
            *(float4*)&gg[4] = *(const float4*)(g + 4);
            #pragma unroll
            for (int j = 0; j < 8; ++j) x[j] *= gg[j];
        }
        u16x8 hv, lv;
        #pragma unroll
        for (int j = 0; j < 8; ++j) {
            unsigned short h, lo;
            split2(x[j], h, lo);
            hv[j] = h; lv[j] = lo;
        }
        const size_t o = (((size_t)mt * 64 + kp) * 128 + row) * 8;
        *(u16x8*)&oh[o] = hv;
        *(u16x8*)&ol[o] = lv;
    }
}

// ---------------------------------------------------------------------------
// bf16 split-3 MFMA GEMM.  out[m,n] = sum_k A[m,k]*W[n,k] + bias[n], fp32 out.
// ---------------------------------------------------------------------------
template<int KT1, int KT2>
__global__ __launch_bounds__(256)
void gemm_bf16s(const unsigned short* __restrict__ A1h, const unsigned short* __restrict__ A1l,
                const unsigned short* __restrict__ A2h, const unsigned short* __restrict__ A2l,
                const unsigned short* __restrict__ Bh,  const unsigned short* __restrict__ Bl,
                const float* __restrict__ bias, float* __restrict__ out)
{
    constexpr int KT = KT1 + KT2;
    __shared__ __align__(16) unsigned short sAh[4096], sAl[4096], sBh[4096], sBl[4096];
    const int tid = threadIdx.x;
    const int nt = blockIdx.x;            // 0..3
    const int mt = blockIdx.y;            // 0..255
    const int n0 = nt * 128, m0 = mt * 128;
    const int l = tid & 63, w = tid >> 6;
    const int wm = w >> 1, wn = w & 1;
    const int so = w * 1024 + (l << 4);   // staging byte offset (wave chunk + lane*16)

    f32x4 acc[4][4] = {};

    uint4 rAh0, rAh1, rAl0, rAl1, rBh0, rBh1, rBl0, rBl1;
    auto loadTile = [&](int kt) {
        const char *ah, *al;
        if (KT2 == 0 || kt < KT1) {
            const size_t o = ((size_t)mt * KT1 + kt) * 8192;
            ah = (const char*)A1h + o; al = (const char*)A1l + o;
        } else {
            const size_t o = ((size_t)mt * KT2 + (kt - KT1)) * 8192;
            ah = (const char*)A2h + o; al = (const char*)A2l + o;
        }
        const size_t ob = ((size_t)nt * KT + kt) * 8192;
        const char* bh = (const char*)Bh + ob;
        const char* bl = (const char*)Bl + ob;
        rAh0 = *(const uint4*)(ah + so); rAh1 = *(const uint4*)(ah + so + 4096);
        rAl0 = *(const uint4*)(al + so); rAl1 = *(const uint4*)(al + so + 4096);
        rBh0 = *(const uint4*)(bh + so); rBh1 = *(const uint4*)(bh + so + 4096);
        rBl0 = *(const uint4*)(bl + so); rBl1 = *(const uint4*)(bl + so + 4096);
    };
    loadTile(0);

    for (int kt = 0; kt < KT; ++kt) {
        __syncthreads();   // prior iteration's LDS reads complete
        *(uint4*)((char*)sAh + so) = rAh0; *(uint4*)((char*)sAh + so + 4096) = rAh1;
        *(uint4*)((char*)sAl + so) = rAl0; *(uint4*)((char*)sAl + so + 4096) = rAl1;
        *(uint4*)((char*)sBh + so) = rBh0; *(uint4*)((char*)sBh + so + 4096) = rBh1;
        *(uint4*)((char*)sBl + so) = rBl0; *(uint4*)((char*)sBl + so + 4096) = rBl1;
        __syncthreads();   // LDS ready
        if (kt + 1 < KT) loadTile(kt + 1);   // prefetch overlaps MFMAs

        const int g = l >> 4;
        const int rA = wm * 64 + (l & 15);
        const int rB = wn * 64 + (l & 15);
        const bf16x8* vAh = (const bf16x8*)sAh; const bf16x8* vAl = (const bf16x8*)sAl;
        const bf16x8* vBh = (const bf16x8*)sBh; const bf16x8* vBl = (const bf16x8*)sBl;
        bf16x8 ah[4], al[4], bh[4], bl[4];
        #pragma unroll
        for (int f = 0; f < 4; ++f) {
            ah[f] = vAh[g * 128 + rA + f * 16];
            al[f] = vAl[g * 128 + rA + f * 16];
            bh[f] = vBh[g * 128 + rB + f * 16];
            bl[f] = vBl[g * 128 + rB + f * 16];
        }
        #pragma unroll
        for (int i = 0; i < 4; ++i)
            #pragma unroll
            for (int j = 0; j < 4; ++j) {
                acc[i][j] = __builtin_amdgcn_mfma_f32_16x16x32_bf16(ah[i], bh[j], acc[i][j], 0, 0, 0);
                acc[i][j] = __builtin_amdgcn_mfma_f32_16x16x32_bf16(ah[i], bl[j], acc[i][j], 0, 0, 0);
                acc[i][j] = __builtin_amdgcn_mfma_f32_16x16x32_bf16(al[i], bh[j], acc[i][j], 0, 0, 0);
            }
    }

    // epilogue: C/D layout col = lane&15, row = (lane>>4)*4 + reg  [m89/m91]
    const int rowb = (l >> 4) * 4, colb = l & 15;
    #pragma unroll
    for (int j = 0; j < 4; ++j) {
        const int c = n0 + wn * 64 + j * 16 + colb;
        const float bv = bias[c];
        #pragma unroll
        for (int i = 0; i < 4; ++i) {
            const int r = m0 + wm * 64 + i * 16 + rowb;
            #pragma unroll
            for (int e = 0; e < 4; ++e)
                out[(size_t)(r + e) * CC + c] = acc[i][j][e] + bv;
        }
    }
}

// ---------------------------------------------------------------------------
// Pooling, split for parallelism (old single-kernel pool was 5.9% occupancy,
// 356 us). scores -> softmax -> partial weighted sums -> combine.
// ---------------------------------------------------------------------------
__global__ __launch_bounds__(256)
void pool_scores(const float* __restrict__ src, const float* __restrict__ wvec,
                 const float* __restrict__ bscal, float* __restrict__ scores, int modeK)
{
    const int nh = blockIdx.x, chunk = blockIdx.y;
    const int n = nh >> 3, h = nh & 7;
    const int tid = threadIdx.x;
    const int wave = tid >> 6, lane = tid & 63;
    const int sub = lane >> 4;          // row-in-group 0..3
    const int c4 = (lane & 15) * 4;     // channel offset
    const float b = bscal[0];
    const float* wv = modeK ? (wvec + nh * 64) : wvec;
    const float4 w4 = *(const float4*)&wv[c4];
    const float* base = src + (size_t)n * LL * CC + h * 64;
    const int l0 = chunk * 128 + wave * 32;
    #pragma unroll
    for (int it = 0; it < 8; ++it) {
        const int ll = l0 + it * 4 + sub;
        const float4 x = *(const float4*)&base[(size_t)ll * CC + c4];
        float s = x.x * w4.x + x.y * w4.y + x.z * w4.z + x.w * w4.w;
        s += __shfl_xor(s, 1, 64);
        s += __shfl_xor(s, 2, 64);
        s += __shfl_xor(s, 4, 64);
        s += __shfl_xor(s, 8, 64);
        if ((lane & 15) == 0) scores[nh * LL + ll] = (s + b) * 0.125f;
    }
}

__global__ __launch_bounds__(256)
void pool_softmax(float* __restrict__ scores)
{
    __shared__ float sc[2048];
    __shared__ float red[8];
    const int nh = blockIdx.x;
    const int tid = threadIdx.x;
    const int wave = tid >> 6, lane = tid & 63;
    float mx = -INFINITY;
    for (int i = tid; i < LL; i += 256) {
        const float v = scores[nh * LL + i];
        sc[i] = v;
        mx = fmaxf(mx, v);
    }
    #pragma unroll
    for (int off = 32; off > 0; off >>= 1) mx = fmaxf(mx, __shfl_xor(mx, off, 64));
    if (lane == 0) red[wave] = mx;
    __syncthreads();
    mx = fmaxf(fmaxf(red[0], red[1]), fmaxf(red[2], red[3]));
    float e[8], sum = 0.f;
    #pragma unroll
    for (int j = 0; j < 8; ++j) {
        e[j] = expf(sc[tid + j * 256] - mx);
        sum += e[j];
    }
    #pragma unroll
    for (int off = 32; off > 0; off >>= 1) sum += __shfl_xor(sum, off, 64);
    if (lane == 0) red[4 + wave] = sum;
    __syncthreads();
    const float inv = 1.f / (red[4] + red[5] + red[6] + red[7]);
    #pragma unroll
    for (int j = 0; j < 8; ++j) scores[nh * LL + tid + j * 256] = e[j] * inv;
}

__global__ __launch_bounds__(256)
void pool_wsum(const float* __restrict__ src, const float* __restrict__ scores,
               float* __restrict__ partials)
{
    __shared__ float sm[256];
    const int nh = blockIdx.x, chunk = blockIdx.y;
    const int n = nh >> 3, h = nh & 7;
    const int tid = threadIdx.x;
    const int wave = tid >> 6, d = tid & 63;
    const float* base = src + (size_t)n * LL * CC + h * 64;
    const int l0 = chunk * 128 + wave * 32;
    float acc = 0.f;
    for (int r = 0; r < 32; ++r) {
        const int ll = l0 + r;
        acc += scores[nh * LL + ll] * base[(size_t)ll * CC + d];
    }
    sm[tid] = acc;
    __syncthreads();
    if (wave == 0) {
        const float p = sm[d] + sm[64 + d] + sm[128 + d] + sm[192 + d];
        partials[((size_t)nh * 16 + chunk) * 64 + d] = p;
    }
}

__global__ __launch_bounds__(64)
void pool_combine(const float* __restrict__ partials, const float* __restrict__ postmul,
                  float* __restrict__ pooled)
{
    const int nh = blockIdx.x, d = threadIdx.x;
    float p = 0.f;
    #pragma unroll
    for (int c = 0; c < 16; ++c) p += partials[((size_t)nh * 16 + c) * 64 + d];
    if (postmul) p *= postmul[d];
    pooled[nh * 64 + d] = p;
}

// ---------------------------------------------------------------------------
// ws byte offsets (~198 MB total, unchanged envelope)
// ---------------------------------------------------------------------------
#define OFF_BQH   0ull
#define OFF_BQL   524288ull
#define OFF_BKH   1048576ull
#define OFF_BKL   1572864ull
#define OFF_BVH   2097152ull
#define OFF_BVL   2621440ull
#define OFF_WBH   3145728ull
#define OFF_WBL   4194304ull
#define OFF_CVEC  5242880ull
#define OFF_GQ    5259264ull
#define OFF_PK    5292032ull
#define OFF_PART  5324800ull       // 512KB, fits pre-existing gap to 6291456
#define OFF_SC    0ull             // 1MB score buffer aliases Bqh/Bql (dead after gemm_q / gemm_k)
#define OFF_APKH  6291456ull       // 32MB
#define OFF_APKL  39845888ull      // 32MB
#define OFF_QBUF  73400320ull      // 64MB fp32 q
#define OFF_KV    140509184ull     // 64MB fp32 k/v, later Qp_hi+Qp_lo
#define OFF_QPH   140509184ull
#define OFF_QPL   174063616ull

extern "C" void kernel_launch(void* const* d_in, const int* in_sizes, int n_in,
                              void* d_out, int out_size, void* d_ws, size_t ws_size,
                              hipStream_t stream) {
    const float* x_q  = (const float*)d_in[0];
    const float* x_kv = (const float*)d_in[1];
    const float* Wq   = (const float*)d_in[2];
    const float* bq   = (const float*)d_in[3];
    const float* wqa  = (const float*)d_in[4];
    const float* bqa  = (const float*)d_in[5];
    const float* Wk   = (const float*)d_in[6];
    const float* bk   = (const float*)d_in[7];
    const float* wka  = (const float*)d_in[8];
    const float* bka  = (const float*)d_in[9];
    const float* Wv   = (const float*)d_in[10];
    const float* bv   = (const float*)d_in[11];
    const float* Wt   = (const float*)d_in[12];
    const float* bt   = (const float*)d_in[13];
    const float* Wp   = (const float*)d_in[14];
    const float* bp   = (const float*)d_in[15];
    float* out = (float*)d_out;
    char* ws = (char*)d_ws;

    unsigned short* Bqh = (unsigned short*)(ws + OFF_BQH);
    unsigned short* Bql = (unsigned short*)(ws + OFF_BQL);
    unsigned short* Bkh = (unsigned short*)(ws + OFF_BKH);
    unsigned short* Bkl = (unsigned short*)(ws + OFF_BKL);
    unsigned short* Bvh = (unsigned short*)(ws + OFF_BVH);
    unsigned short* Bvl = (unsigned short*)(ws + OFF_BVL);
    unsigned short* WBh = (unsigned short*)(ws + OFF_WBH);
    unsigned short* WBl = (unsigned short*)(ws + OFF_WBL);
    float* cvec = (float*)(ws + OFF_CVEC);
    float* gq   = (float*)(ws + OFF_GQ);
    float* pk   = (float*)(ws + OFF_PK);
    float* part = (float*)(ws + OFF_PART);
    float* sc   = (float*)(ws + OFF_SC);
    unsigned short* APh = (unsigned short*)(ws + OFF_APKH);
    unsigned short* APl = (unsigned short*)(ws + OFF_APKL);
    float* qbuf  = (float*)(ws + OFF_QBUF);
    float* kvbuf = (float*)(ws + OFF_KV);
    unsigned short* QPh = (unsigned short*)(ws + OFF_QPH);
    unsigned short* QPl = (unsigned short*)(ws + OFF_QPL);

    const dim3 ggrid(4, 256);
    const dim3 pgrid(NB * HH, 16);

    // 1. weight prep (packed hi/lo + Wt-fold + cvec)
    prep_kernel<<<2048, 256, 0, stream>>>(Wq, Wk, Wv, Wt, bt, Wp, bp,
                                          Bqh, Bql, Bkh, Bkl, Bvh, Bvl, WBh, WBl, cvec);
    // 2. pack x_q
    convert_pack<<<256, 256, 0, stream>>>(x_q, nullptr, APh, APl);
    // 3. q projection (MFMA)
    gemm_bf16s<16, 0><<<ggrid, 256, 0, stream>>>(APh, APl, nullptr, nullptr, Bqh, Bql, bq, qbuf);
    // 4. q pooling -> gq = pooled_q * wka   (sc aliases Bq: dead after step 3)
    pool_scores<<<pgrid, 256, 0, stream>>>(qbuf, wqa, bqa, sc, 0);
    pool_softmax<<<NB * HH, 256, 0, stream>>>(sc);
    pool_wsum<<<pgrid, 256, 0, stream>>>(qbuf, sc, part);
    pool_combine<<<NB * HH, 64, 0, stream>>>(part, wka, gq);
    // 5. pack x_kv (over x_q packing)
    convert_pack<<<256, 256, 0, stream>>>(x_kv, nullptr, APh, APl);
    // 6. k projection
    gemm_bf16s<16, 0><<<ggrid, 256, 0, stream>>>(APh, APl, nullptr, nullptr, Bkh, Bkl, bk, kvbuf);
    // 7. k pooling -> pooled_k [16][512]   (sc aliases Bk region too: dead after step 6)
    pool_scores<<<pgrid, 256, 0, stream>>>(kvbuf, gq, bka, sc, 1);
    pool_softmax<<<NB * HH, 256, 0, stream>>>(sc);
    pool_wsum<<<pgrid, 256, 0, stream>>>(kvbuf, sc, part);
    pool_combine<<<NB * HH, 64, 0, stream>>>(part, nullptr, pk);
    // 8. v projection (same packed x_kv; overwrite kvbuf with v)
    gemm_bf16s<16, 0><<<ggrid, 256, 0, stream>>>(APh, APl, nullptr, nullptr, Bvh, Bvl, bv, kvbuf);
    // 9. pack v * pooled_k (over x_kv packing)
    convert_pack<<<256, 256, 0, stream>>>(kvbuf, pk, APh, APl);
    // 10. pack q (over kvbuf... separate region)
    convert_pack<<<256, 256, 0, stream>>>(qbuf, nullptr, QPh, QPl);
    // 11. fused final: (v*pk)@Wbig + q@WpT + cvec
    gemm_bf16s<16, 16><<<ggrid, 256, 0, stream>>>(APh, APl, QPh, QPl, WBh, WBl, cvec, out);
}

// Round 4
// 587.416 us; speedup vs baseline: 3.1735x; 1.1941x over previous
//
#include <hip/hip_runtime.h>
#include <hip/hip_bf16.h>
#include <math.h>

// Problem constants
#define NB 16
#define LL 2048
#define CC 512
#define HH 8
#define MM (NB*LL)          // 32768

typedef __attribute__((ext_vector_type(8))) short bf16x8;
typedef __attribute__((ext_vector_type(4))) float f32x4;
typedef __attribute__((ext_vector_type(8))) unsigned short u16x8;

// ---------------------------------------------------------------------------
// bf16 split helpers: x ≈ hi + lo, both bf16. Missing term lo*lo ~ 2^-18 rel.
// ---------------------------------------------------------------------------
__device__ inline unsigned short f2bf(float x) {
    __hip_bfloat16 b = __float2bfloat16(x);
    return __builtin_bit_cast(unsigned short, b);
}
__device__ inline float bf2f(unsigned short u) {
    __hip_bfloat16 b = __builtin_bit_cast(__hip_bfloat16, u);
    return __bfloat162float(b);
}
__device__ inline void split2(float x, unsigned short& h, unsigned short& l) {
    unsigned short hh = f2bf(x);
    float fh = bf2f(hh);
    h = hh;
    l = f2bf(x - fh);
}

// ---------------------------------------------------------------------------
// Prep: pack weights (hi/lo, fragment-packed [nt][kp][n%128][k%8]) + fold Wt
// into Wp -> WB, cvec = bp + (bt broadcast) @ Wp^T.
// ---------------------------------------------------------------------------
__global__ __launch_bounds__(256)
void prep_kernel(const float* __restrict__ Wq, const float* __restrict__ Wk,
                 const float* __restrict__ Wv, const float* __restrict__ Wt,
                 const float* __restrict__ bt, const float* __restrict__ Wp,
                 const float* __restrict__ bp,
                 unsigned short* __restrict__ Bqh, unsigned short* __restrict__ Bql,
                 unsigned short* __restrict__ Bkh, unsigned short* __restrict__ Bkl,
                 unsigned short* __restrict__ Bvh, unsigned short* __restrict__ Bvl,
                 unsigned short* __restrict__ WBh, unsigned short* __restrict__ WBl,
                 float* __restrict__ cvec)
{
    const int t = blockIdx.x * 256 + threadIdx.x;   // 512*1024 threads
    const int c = t >> 10;         // output col n, 0..511
    const int k = t & 1023;        // virtual K, 0..1023
    float val;
    if (k < 512) {   // Wbig[k=h*64+d][c] = sum_e Wt[e][d] * Wp[c][h*64+e]
        const int h = k >> 6, d = k & 63;
        float s = 0.f;
        #pragma unroll 8
        for (int e = 0; e < 64; ++e) s += Wt[e * 64 + d] * Wp[c * CC + h * 64 + e];
        val = s;
    } else {         // WpT rows
        val = Wp[c * CC + (k - 512)];
    }
    unsigned short hh, ll;
    split2(val, hh, ll);
    const size_t pw = (((size_t)(c >> 7) * 128 + (k >> 3)) * 128 + (c & 127)) * 8 + (k & 7);
    WBh[pw] = hh; WBl[pw] = ll;
    if (k < 512) {
        const size_t pq = (((size_t)(c >> 7) * 64 + (k >> 3)) * 128 + (c & 127)) * 8 + (k & 7);
        split2(Wq[c * CC + k], hh, ll); Bqh[pq] = hh; Bql[pq] = ll;
        split2(Wk[c * CC + k], hh, ll); Bkh[pq] = hh; Bkl[pq] = ll;
        split2(Wv[c * CC + k], hh, ll); Bvh[pq] = hh; Bvl[pq] = ll;
    }
    if (k == 0) {
        float cv = bp[c];
        for (int j = 0; j < 512; ++j) cv += bt[j & 63] * Wp[c * CC + j];
        cvec[c] = cv;
    }
}

// ---------------------------------------------------------------------------
// bf16 split-3 MFMA GEMM with fp32 A staged directly from HBM (register split
// during LDS staging — removes the convert_pack passes entirely).
// out[m,n] = sum_k A[m,k]*W[n,k] + bias[n], fp32 out.
// Virtual K = KT1 ktiles from A1 (optionally gated per-sample) then KT2 from
// A2. ktile = 32 k. 128x128 tile, 4 waves, 4x4 frags 16x16x32, 48 MFMA/ktile.
// ---------------------------------------------------------------------------
template<int KT1, int KT2, bool G1>
__global__ __launch_bounds__(256)
void gemm_f32a(const float* __restrict__ A1, const float* __restrict__ A2,
               const float* __restrict__ gate,
               const unsigned short* __restrict__ Bh, const unsigned short* __restrict__ Bl,
               const float* __restrict__ bias, float* __restrict__ out)
{
    constexpr int KT = KT1 + KT2;
    __shared__ __align__(16) unsigned short sAh[4096], sAl[4096], sBh[4096], sBl[4096];
    const int tid = threadIdx.x;
    const int nt = blockIdx.x;            // 0..3
    const int mt = blockIdx.y;            // 0..255
    const int n0 = nt * 128, m0 = mt * 128;
    const int l = tid & 63, w = tid >> 6;
    const int wm = w >> 1, wn = w & 1;
    const int so = w * 1024 + (l << 4);   // B staging byte offset (contiguous 16B/lane)
    const int smp = mt >> 4;              // sample index (128 | 2048)

    f32x4 acc[4][4] = {};

    float4 pa0, pa1, pa2, pa3;            // A prefetch: [it0](lo,hi) [it1](lo,hi)
    uint4 rbh0, rbh1, rbl0, rbl1;

    auto loadTile = [&](int kt) {
        const float* Asrc; int k0; bool g;
        if (KT2 == 0 || kt < KT1) { Asrc = A1; k0 = kt * 32; g = G1; }
        else                      { Asrc = A2; k0 = (kt - KT1) * 32; g = false; }
        {
            const int row = tid & 127, kp = tid >> 7;          // it = 0
            const float* p = Asrc + (size_t)(m0 + row) * CC + k0 + kp * 8;
            float4 a0 = *(const float4*)p, a1 = *(const float4*)(p + 4);
            if (g) {
                const float* gp = gate + smp * CC + k0 + kp * 8;
                const float4 g0 = *(const float4*)gp, g1 = *(const float4*)(gp + 4);
                a0.x *= g0.x; a0.y *= g0.y; a0.z *= g0.z; a0.w *= g0.w;
                a1.x *= g1.x; a1.y *= g1.y; a1.z *= g1.z; a1.w *= g1.w;
            }
            pa0 = a0; pa1 = a1;
        }
        {
            const int idx = 256 + tid;                          // it = 1
            const int row = idx & 127, kp = idx >> 7;
            const float* p = Asrc + (size_t)(m0 + row) * CC + k0 + kp * 8;
            float4 a0 = *(const float4*)p, a1 = *(const float4*)(p + 4);
            if (g) {
                const float* gp = gate + smp * CC + k0 + kp * 8;
                const float4 g0 = *(const float4*)gp, g1 = *(const float4*)(gp + 4);
                a0.x *= g0.x; a0.y *= g0.y; a0.z *= g0.z; a0.w *= g0.w;
                a1.x *= g1.x; a1.y *= g1.y; a1.z *= g1.z; a1.w *= g1.w;
            }
            pa2 = a0; pa3 = a1;
        }
        const size_t ob = ((size_t)nt * KT + kt) * 8192;
        const char* bh = (const char*)Bh + ob;
        const char* bl = (const char*)Bl + ob;
        rbh0 = *(const uint4*)(bh + so); rbh1 = *(const uint4*)(bh + so + 4096);
        rbl0 = *(const uint4*)(bl + so); rbl1 = *(const uint4*)(bl + so + 4096);
    };

    auto storeTile = [&]() {
        {
            const int row = tid & 127, kp = tid >> 7;
            float x[8];
            *(float4*)&x[0] = pa0; *(float4*)&x[4] = pa1;
            u16x8 hv, lv;
            #pragma unroll
            for (int j = 0; j < 8; ++j) { unsigned short h, lo; split2(x[j], h, lo); hv[j] = h; lv[j] = lo; }
            *(u16x8*)&sAh[(kp * 128 + row) * 8] = hv;
            *(u16x8*)&sAl[(kp * 128 + row) * 8] = lv;
        }
        {
            const int idx = 256 + tid;
            const int row = idx & 127, kp = idx >> 7;
            float x[8];
            *(float4*)&x[0] = pa2; *(float4*)&x[4] = pa3;
            u16x8 hv, lv;
            #pragma unroll
            for (int j = 0; j < 8; ++j) { unsigned short h, lo; split2(x[j], h, lo); hv[j] = h; lv[j] = lo; }
            *(u16x8*)&sAh[(kp * 128 + row) * 8] = hv;
            *(u16x8*)&sAl[(kp * 128 + row) * 8] = lv;
        }
        *(uint4*)((char*)sBh + so) = rbh0; *(uint4*)((char*)sBh + so + 4096) = rbh1;
        *(uint4*)((char*)sBl + so) = rbl0; *(uint4*)((char*)sBl + so + 4096) = rbl1;
    };

    loadTile(0);

    for (int kt = 0; kt < KT; ++kt) {
        __syncthreads();   // prior iteration's LDS reads complete
        storeTile();
        __syncthreads();   // LDS ready
        if (kt + 1 < KT) loadTile(kt + 1);   // prefetch overlaps MFMAs

        const int g = l >> 4;
        const int rA = wm * 64 + (l & 15);
        const int rB = wn * 64 + (l & 15);
        const bf16x8* vAh = (const bf16x8*)sAh; const bf16x8* vAl = (const bf16x8*)sAl;
        const bf16x8* vBh = (const bf16x8*)sBh; const bf16x8* vBl = (const bf16x8*)sBl;
        bf16x8 ah[4], al[4], bh[4], bl[4];
        #pragma unroll
        for (int f = 0; f < 4; ++f) {
            ah[f] = vAh[g * 128 + rA + f * 16];
            al[f] = vAl[g * 128 + rA + f * 16];
            bh[f] = vBh[g * 128 + rB + f * 16];
            bl[f] = vBl[g * 128 + rB + f * 16];
        }
        #pragma unroll
        for (int i = 0; i < 4; ++i)
            #pragma unroll
            for (int j = 0; j < 4; ++j) {
                acc[i][j] = __builtin_amdgcn_mfma_f32_16x16x32_bf16(ah[i], bh[j], acc[i][j], 0, 0, 0);
                acc[i][j] = __builtin_amdgcn_mfma_f32_16x16x32_bf16(ah[i], bl[j], acc[i][j], 0, 0, 0);
                acc[i][j] = __builtin_amdgcn_mfma_f32_16x16x32_bf16(al[i], bh[j], acc[i][j], 0, 0, 0);
            }
    }

    // epilogue: C/D layout col = lane&15, row = (lane>>4)*4 + reg  [m89/m91]
    const int rowb = (l >> 4) * 4, colb = l & 15;
    #pragma unroll
    for (int j = 0; j < 4; ++j) {
        const int c = n0 + wn * 64 + j * 16 + colb;
        const float bv = bias[c];
        #pragma unroll
        for (int i = 0; i < 4; ++i) {
            const int r = m0 + wm * 64 + i * 16 + rowb;
            #pragma unroll
            for (int e = 0; e < 4; ++e)
                out[(size_t)(r + e) * CC + c] = acc[i][j][e] + bv;
        }
    }
}

// ---------------------------------------------------------------------------
// Pooling, split for parallelism: scores -> softmax -> partials -> combine.
// ---------------------------------------------------------------------------
__global__ __launch_bounds__(256)
void pool_scores(const float* __restrict__ src, const float* __restrict__ wvec,
                 const float* __restrict__ bscal, float* __restrict__ scores, int modeK)
{
    const int nh = blockIdx.x, chunk = blockIdx.y;
    const int n = nh >> 3, h = nh & 7;
    const int tid = threadIdx.x;
    const int wave = tid >> 6, lane = tid & 63;
    const int sub = lane >> 4;          // row-in-group 0..3
    const int c4 = (lane & 15) * 4;     // channel offset
    const float b = bscal[0];
    const float* wv = modeK ? (wvec + nh * 64) : wvec;
    const float4 w4 = *(const float4*)&wv[c4];
    const float* base = src + (size_t)n * LL * CC + h * 64;
    const int l0 = chunk * 128 + wave * 32;
    #pragma unroll
    for (int it = 0; it < 8; ++it) {
        const int ll = l0 + it * 4 + sub;
        const float4 x = *(const float4*)&base[(size_t)ll * CC + c4];
        float s = x.x * w4.x + x.y * w4.y + x.z * w4.z + x.w * w4.w;
        s += __shfl_xor(s, 1, 64);
        s += __shfl_xor(s, 2, 64);
        s += __shfl_xor(s, 4, 64);
        s += __shfl_xor(s, 8, 64);
        if ((lane & 15) == 0) scores[nh * LL + ll] = (s + b) * 0.125f;
    }
}

__global__ __launch_bounds__(256)
void pool_softmax(float* __restrict__ scores)
{
    __shared__ float sc[2048];
    __shared__ float red[8];
    const int nh = blockIdx.x;
    const int tid = threadIdx.x;
    const int wave = tid >> 6, lane = tid & 63;
    float mx = -INFINITY;
    for (int i = tid; i < LL; i += 256) {
        const float v = scores[nh * LL + i];
        sc[i] = v;
        mx = fmaxf(mx, v);
    }
    #pragma unroll
    for (int off = 32; off > 0; off >>= 1) mx = fmaxf(mx, __shfl_xor(mx, off, 64));
    if (lane == 0) red[wave] = mx;
    __syncthreads();
    mx = fmaxf(fmaxf(red[0], red[1]), fmaxf(red[2], red[3]));
    float e[8], sum = 0.f;
    #pragma unroll
    for (int j = 0; j < 8; ++j) {
        e[j] = expf(sc[tid + j * 256] - mx);
        sum += e[j];
    }
    #pragma unroll
    for (int off = 32; off > 0; off >>= 1) sum += __shfl_xor(sum, off, 64);
    if (lane == 0) red[4 + wave] = sum;
    __syncthreads();
    const float inv = 1.f / (red[4] + red[5] + red[6] + red[7]);
    #pragma unroll
    for (int j = 0; j < 8; ++j) scores[nh * LL + tid + j * 256] = e[j] * inv;
}

__global__ __launch_bounds__(256)
void pool_wsum(const float* __restrict__ src, const float* __restrict__ scores,
               float* __restrict__ partials)
{
    __shared__ float sm[256];
    const int nh = blockIdx.x, chunk = blockIdx.y;
    const int n = nh >> 3, h = nh & 7;
    const int tid = threadIdx.x;
    const int wave = tid >> 6, d = tid & 63;
    const float* base = src + (size_t)n * LL * CC + h * 64;
    const int l0 = chunk * 128 + wave * 32;
    float acc = 0.f;
    for (int r = 0; r < 32; ++r) {
        const int ll = l0 + r;
        acc += scores[nh * LL + ll] * base[(size_t)ll * CC + d];
    }
    sm[tid] = acc;
    __syncthreads();
    if (wave == 0) {
        const float p = sm[d] + sm[64 + d] + sm[128 + d] + sm[192 + d];
        partials[((size_t)nh * 16 + chunk) * 64 + d] = p;
    }
}

__global__ __launch_bounds__(64)
void pool_combine(const float* __restrict__ partials, const float* __restrict__ postmul,
                  float* __restrict__ pooled)
{
    const int nh = blockIdx.x, d = threadIdx.x;
    float p = 0.f;
    #pragma unroll
    for (int c = 0; c < 16; ++c) p += partials[((size_t)nh * 16 + c) * 64 + d];
    if (postmul) p *= postmul[d];
    pooled[nh * 64 + d] = p;
}

// ---------------------------------------------------------------------------
// ws byte offsets (~140 MB total; converts removed)
// ---------------------------------------------------------------------------
#define OFF_BQH   0ull
#define OFF_BQL   524288ull
#define OFF_BKH   1048576ull
#define OFF_BKL   1572864ull
#define OFF_BVH   2097152ull
#define OFF_BVL   2621440ull
#define OFF_WBH   3145728ull
#define OFF_WBL   4194304ull
#define OFF_CVEC  5242880ull
#define OFF_GQ    5259264ull
#define OFF_PK    5292032ull
#define OFF_PART  5324800ull       // 512KB
#define OFF_SC    0ull             // 1MB score buffer aliases Bqh/Bql (dead when pooling runs)
#define OFF_QBUF  6291456ull       // 64MB fp32 q
#define OFF_KV    73400320ull      // 64MB fp32 k then v

extern "C" void kernel_launch(void* const* d_in, const int* in_sizes, int n_in,
                              void* d_out, int out_size, void* d_ws, size_t ws_size,
                              hipStream_t stream) {
    const float* x_q  = (const float*)d_in[0];
    const float* x_kv = (const float*)d_in[1];
    const float* Wq   = (const float*)d_in[2];
    const float* bq   = (const float*)d_in[3];
    const float* wqa  = (const float*)d_in[4];
    const float* bqa  = (const float*)d_in[5];
    const float* Wk   = (const float*)d_in[6];
    const float* bk   = (const float*)d_in[7];
    const float* wka  = (const float*)d_in[8];
    const float* bka  = (const float*)d_in[9];
    const float* Wv   = (const float*)d_in[10];
    const float* bv   = (const float*)d_in[11];
    const float* Wt   = (const float*)d_in[12];
    const float* bt   = (const float*)d_in[13];
    const float* Wp   = (const float*)d_in[14];
    const float* bp   = (const float*)d_in[15];
    float* out = (float*)d_out;
    char* ws = (char*)d_ws;

    unsigned short* Bqh = (unsigned short*)(ws + OFF_BQH);
    unsigned short* Bql = (unsigned short*)(ws + OFF_BQL);
    unsigned short* Bkh = (unsigned short*)(ws + OFF_BKH);
    unsigned short* Bkl = (unsigned short*)(ws + OFF_BKL);
    unsigned short* Bvh = (unsigned short*)(ws + OFF_BVH);
    unsigned short* Bvl = (unsigned short*)(ws + OFF_BVL);
    unsigned short* WBh = (unsigned short*)(ws + OFF_WBH);
    unsigned short* WBl = (unsigned short*)(ws + OFF_WBL);
    float* cvec = (float*)(ws + OFF_CVEC);
    float* gq   = (float*)(ws + OFF_GQ);
    float* pk   = (float*)(ws + OFF_PK);
    float* part = (float*)(ws + OFF_PART);
    float* sc   = (float*)(ws + OFF_SC);
    float* qbuf  = (float*)(ws + OFF_QBUF);
    float* kvbuf = (float*)(ws + OFF_KV);

    const dim3 ggrid(4, 256);
    const dim3 pgrid(NB * HH, 16);

    // 1. weight prep (packed hi/lo + Wt-fold + cvec)
    prep_kernel<<<2048, 256, 0, stream>>>(Wq, Wk, Wv, Wt, bt, Wp, bp,
                                          Bqh, Bql, Bkh, Bkl, Bvh, Bvl, WBh, WBl, cvec);
    // 2. q projection (fp32 A staged+split in-kernel)
    gemm_f32a<16, 0, false><<<ggrid, 256, 0, stream>>>(x_q, nullptr, nullptr, Bqh, Bql, bq, qbuf);
    // 3. q pooling -> gq = pooled_q * wka   (sc aliases Bq: dead after step 2)
    pool_scores<<<pgrid, 256, 0, stream>>>(qbuf, wqa, bqa, sc, 0);
    pool_softmax<<<NB * HH, 256, 0, stream>>>(sc);
    pool_wsum<<<pgrid, 256, 0, stream>>>(qbuf, sc, part);
    pool_combine<<<NB * HH, 64, 0, stream>>>(part, wka, gq);
    // 4. k projection
    gemm_f32a<16, 0, false><<<ggrid, 256, 0, stream>>>(x_kv, nullptr, nullptr, Bkh, Bkl, bk, kvbuf);
    // 5. k pooling -> pooled_k [16][512]
    pool_scores<<<pgrid, 256, 0, stream>>>(kvbuf, gq, bka, sc, 1);
    pool_softmax<<<NB * HH, 256, 0, stream>>>(sc);
    pool_wsum<<<pgrid, 256, 0, stream>>>(kvbuf, sc, part);
    pool_combine<<<NB * HH, 64, 0, stream>>>(part, nullptr, pk);
    // 6. v projection (k dead after pooling; overwrite kvbuf with v)
    gemm_f32a<16, 0, false><<<ggrid, 256, 0, stream>>>(x_kv, nullptr, nullptr, Bvh, Bvl, bv, kvbuf);
    // 7. fused final: (v*pk)@Wbig + q@WpT + cvec  (gate applied in A1 staging)
    gemm_f32a<16, 16, true><<<ggrid, 256, 0, stream>>>(kvbuf, qbuf, pk, WBh, WBl, cvec, out);
}

// Round 5
// 517.293 us; speedup vs baseline: 3.6037x; 1.1356x over previous
//
#include <hip/hip_runtime.h>
#include <hip/hip_bf16.h>
#include <math.h>

// Problem constants
#define NB 16
#define LL 2048
#define CC 512
#define HH 8
#define MM (NB*LL)          // 32768

typedef __attribute__((ext_vector_type(8))) short bf16x8;
typedef __attribute__((ext_vector_type(4))) float f32x4;
typedef __attribute__((ext_vector_type(8))) unsigned short u16x8;

// ---------------------------------------------------------------------------
// bf16 split helpers: x ≈ hi + lo, both bf16. Missing term lo*lo ~ 2^-18 rel.
// ---------------------------------------------------------------------------
__device__ inline unsigned short f2bf(float x) {
    __hip_bfloat16 b = __float2bfloat16(x);
    return __builtin_bit_cast(unsigned short, b);
}
__device__ inline float bf2f(unsigned short u) {
    __hip_bfloat16 b = __builtin_bit_cast(__hip_bfloat16, u);
    return __bfloat162float(b);
}
__device__ inline void split2(float x, unsigned short& h, unsigned short& l) {
    unsigned short hh = f2bf(x);
    float fh = bf2f(hh);
    h = hh;
    l = f2bf(x - fh);
}

// ---------------------------------------------------------------------------
// Prep: pack weights hi/lo as [k>>3][n 0..511][k&7] (k-panel major) + fold Wt
// into Wp -> WB (virtual K=1024), cvec = bp + (bt broadcast) @ Wp^T.
// ---------------------------------------------------------------------------
__global__ __launch_bounds__(256)
void prep_kernel(const float* __restrict__ Wq, const float* __restrict__ Wk,
                 const float* __restrict__ Wv, const float* __restrict__ Wt,
                 const float* __restrict__ bt, const float* __restrict__ Wp,
                 const float* __restrict__ bp,
                 unsigned short* __restrict__ Bqh, unsigned short* __restrict__ Bql,
                 unsigned short* __restrict__ Bkh, unsigned short* __restrict__ Bkl,
                 unsigned short* __restrict__ Bvh, unsigned short* __restrict__ Bvl,
                 unsigned short* __restrict__ WBh, unsigned short* __restrict__ WBl,
                 float* __restrict__ cvec)
{
    const int t = blockIdx.x * 256 + threadIdx.x;   // 512*1024 threads
    const int c = t >> 10;         // output col n, 0..511
    const int k = t & 1023;        // virtual K, 0..1023
    float val;
    if (k < 512) {   // Wbig[k=h*64+d][c] = sum_e Wt[e][d] * Wp[c][h*64+e]
        const int h = k >> 6, d = k & 63;
        float s = 0.f;
        #pragma unroll 8
        for (int e = 0; e < 64; ++e) s += Wt[e * 64 + d] * Wp[c * CC + h * 64 + e];
        val = s;
    } else {         // WpT rows
        val = Wp[c * CC + (k - 512)];
    }
    unsigned short hh, ll;
    split2(val, hh, ll);
    const size_t pw = (((size_t)(k >> 3) * 512) + c) * 8 + (k & 7);
    WBh[pw] = hh; WBl[pw] = ll;
    if (k < 512) {
        split2(Wq[c * CC + k], hh, ll); Bqh[pw] = hh; Bql[pw] = ll;
        split2(Wk[c * CC + k], hh, ll); Bkh[pw] = hh; Bkl[pw] = ll;
        split2(Wv[c * CC + k], hh, ll); Bvh[pw] = hh; Bvl[pw] = ll;
    }
    if (k == 0) {
        float cv = bp[c];
        for (int j = 0; j < 512; ++j) cv += bt[j & 63] * Wp[c * CC + j];
        cvec[c] = cv;
    }
}

// ---------------------------------------------------------------------------
// bf16 split-3 MFMA GEMM, fp32 A staged+split in-kernel.
// BM=128, BN=256, BK=32. 512 threads = 8 waves (2M x 4N), per-wave 64x64 out,
// 4x4 frags of 16x16x32, 48 MFMA/wave/ktile. XCD-grouped swizzle: the two
// nt column-tiles of each mt run back-to-back on the same XCD (A L2 reuse).
// ---------------------------------------------------------------------------
template<int KT1, int KT2, bool G1>
__global__ __launch_bounds__(512, 4)
void gemm_f32a(const float* __restrict__ A1, const float* __restrict__ A2,
               const float* __restrict__ gate,
               const unsigned short* __restrict__ Bh, const unsigned short* __restrict__ Bl,
               const float* __restrict__ bias, float* __restrict__ out)
{
    constexpr int KT = KT1 + KT2;
    __shared__ __align__(16) unsigned short sAh[4096], sAl[4096];   // 128 x 32
    __shared__ __align__(16) unsigned short sBh[8192], sBl[8192];   // 256 x 32
    const int tid = threadIdx.x;
    const int flat = blockIdx.x;              // 512 blocks
    const int xcd = flat & 7, idx = flat >> 3;
    const int mt = xcd * 32 + (idx >> 1);     // 0..255
    const int nt = idx & 1;                   // 0..1
    const int n0 = nt * 256, m0 = mt * 128;
    const int l = tid & 63, w = tid >> 6;
    const int wm = w >> 2, wn = w & 3;        // 2M x 4N waves
    const int smp = mt >> 4;                  // sample (128 | 2048)

    // staging slots
    const int arow = tid & 127, akp = tid >> 7;     // A: 4 kp x 128 rows
    const int bcol = tid & 255, bkp0 = tid >> 8;    // B: slots (bkp0, bkp0+2)

    f32x4 acc[4][4] = {};

    float4 pa0, pa1;
    uint4 pbh0, pbh1, pbl0, pbl1;

    auto loadTile = [&](int kt) {
        const float* Asrc; int k0g; bool g;
        if (KT2 == 0 || kt < KT1) { Asrc = A1; k0g = kt * 32; g = G1; }
        else                      { Asrc = A2; k0g = (kt - KT1) * 32; g = false; }
        const float* p = Asrc + (size_t)(m0 + arow) * CC + k0g + akp * 8;
        float4 a0 = *(const float4*)p, a1 = *(const float4*)(p + 4);
        if (g) {
            const float* gp = gate + smp * CC + k0g + akp * 8;
            const float4 g0 = *(const float4*)gp, g1 = *(const float4*)(gp + 4);
            a0.x *= g0.x; a0.y *= g0.y; a0.z *= g0.z; a0.w *= g0.w;
            a1.x *= g1.x; a1.y *= g1.y; a1.z *= g1.z; a1.w *= g1.w;
        }
        pa0 = a0; pa1 = a1;
        const int kpg = kt * 4;
        const size_t ob0 = (((size_t)(kpg + bkp0) * 512) + n0 + bcol) * 8;
        const size_t ob1 = (((size_t)(kpg + bkp0 + 2) * 512) + n0 + bcol) * 8;
        pbh0 = *(const uint4*)&Bh[ob0]; pbh1 = *(const uint4*)&Bh[ob1];
        pbl0 = *(const uint4*)&Bl[ob0]; pbl1 = *(const uint4*)&Bl[ob1];
    };

    auto storeTile = [&]() {
        float x[8];
        *(float4*)&x[0] = pa0; *(float4*)&x[4] = pa1;
        u16x8 hv, lv;
        #pragma unroll
        for (int j = 0; j < 8; ++j) { unsigned short h, lo; split2(x[j], h, lo); hv[j] = h; lv[j] = lo; }
        *(u16x8*)&sAh[(akp * 128 + arow) * 8] = hv;
        *(u16x8*)&sAl[(akp * 128 + arow) * 8] = lv;
        *(uint4*)&sBh[(bkp0 * 256 + bcol) * 8] = pbh0;
        *(uint4*)&sBh[((bkp0 + 2) * 256 + bcol) * 8] = pbh1;
        *(uint4*)&sBl[(bkp0 * 256 + bcol) * 8] = pbl0;
        *(uint4*)&sBl[((bkp0 + 2) * 256 + bcol) * 8] = pbl1;
    };

    loadTile(0);

    for (int kt = 0; kt < KT; ++kt) {
        __syncthreads();   // prior iteration's LDS reads complete
        storeTile();
        __syncthreads();   // LDS ready
        if (kt + 1 < KT) loadTile(kt + 1);   // prefetch overlaps MFMAs

        const int g = l >> 4;
        const int rA = wm * 64 + (l & 15);
        const int rB = wn * 64 + (l & 15);
        const bf16x8* vAh = (const bf16x8*)sAh; const bf16x8* vAl = (const bf16x8*)sAl;
        const bf16x8* vBh = (const bf16x8*)sBh; const bf16x8* vBl = (const bf16x8*)sBl;
        bf16x8 ah[4], al[4], bh[4], bl[4];
        #pragma unroll
        for (int f = 0; f < 4; ++f) {
            ah[f] = vAh[g * 128 + rA + f * 16];
            al[f] = vAl[g * 128 + rA + f * 16];
            bh[f] = vBh[g * 256 + rB + f * 16];
            bl[f] = vBl[g * 256 + rB + f * 16];
        }
        #pragma unroll
        for (int i = 0; i < 4; ++i)
            #pragma unroll
            for (int j = 0; j < 4; ++j) {
                acc[i][j] = __builtin_amdgcn_mfma_f32_16x16x32_bf16(ah[i], bh[j], acc[i][j], 0, 0, 0);
                acc[i][j] = __builtin_amdgcn_mfma_f32_16x16x32_bf16(ah[i], bl[j], acc[i][j], 0, 0, 0);
                acc[i][j] = __builtin_amdgcn_mfma_f32_16x16x32_bf16(al[i], bh[j], acc[i][j], 0, 0, 0);
            }
    }

    // epilogue: C/D layout col = lane&15, row = (lane>>4)*4 + reg  [m89/m91]
    const int rowb = (l >> 4) * 4, colb = l & 15;
    #pragma unroll
    for (int j = 0; j < 4; ++j) {
        const int c = n0 + wn * 64 + j * 16 + colb;
        const float bv = bias[c];
        #pragma unroll
        for (int i = 0; i < 4; ++i) {
            const int r = m0 + wm * 64 + i * 16 + rowb;
            #pragma unroll
            for (int e = 0; e < 4; ++e)
                out[(size_t)(r + e) * CC + c] = acc[i][j][e] + bv;
        }
    }
}

// ---------------------------------------------------------------------------
// Fused additive pooling, 2 dispatches. Scores are bounded (|s| < ~2), so
// softmax needs no max-subtraction: pooled = sum(e_l * x_l) / sum(e_l).
// stage1: per (nh, chunk of 128 l): e_l = exp((dot(x_l, wv)+b)/8),
//         partial [sum e*x (64d), sum e]. stage2: combine 16 chunks + divide.
// ---------------------------------------------------------------------------
__global__ __launch_bounds__(256)
void pool_stage1(const float* __restrict__ src, const float* __restrict__ wvec,
                 const float* __restrict__ bscal, float* __restrict__ partials,
                 int modeK)
{
    __shared__ float sm[256];
    __shared__ float se[4];
    const int nh = blockIdx.x, chunk = blockIdx.y;
    const int n = nh >> 3, h = nh & 7;
    const int tid = threadIdx.x;
    const int wave = tid >> 6, d = tid & 63;
    const float wv = modeK ? wvec[nh * 64 + d] : wvec[d];
    const float b = bscal[0];
    const float* base = src + (size_t)n * LL * CC + h * 64;
    float accv = 0.f, acce = 0.f;
    const int l0 = chunk * 128 + wave;
    #pragma unroll 4
    for (int it = 0; it < 32; ++it) {
        const int ll = l0 + it * 4;
        const float x = base[(size_t)ll * CC + d];
        float s = x * wv;
        s += __shfl_xor(s, 1, 64);
        s += __shfl_xor(s, 2, 64);
        s += __shfl_xor(s, 4, 64);
        s += __shfl_xor(s, 8, 64);
        s += __shfl_xor(s, 16, 64);
        s += __shfl_xor(s, 32, 64);
        const float e = expf((s + b) * 0.125f);
        accv += e * x;
        acce += e;
    }
    sm[tid] = accv;
    if (d == 0) se[wave] = acce;
    __syncthreads();
    if (wave == 0) {
        const float pv = sm[d] + sm[64 + d] + sm[128 + d] + sm[192 + d];
        float* pr = partials + ((size_t)nh * 16 + chunk) * 65;
        pr[d] = pv;
        if (d == 0) pr[64] = se[0] + se[1] + se[2] + se[3];
    }
}

__global__ __launch_bounds__(64)
void pool_stage2(const float* __restrict__ partials, const float* __restrict__ postmul,
                 float* __restrict__ pooled)
{
    const int nh = blockIdx.x, d = threadIdx.x;
    float pv = 0.f, pe = 0.f;
    #pragma unroll
    for (int c = 0; c < 16; ++c) {
        const float* pr = partials + ((size_t)nh * 16 + c) * 65;
        pv += pr[d];
        pe += pr[64];
    }
    float p = pv / pe;
    if (postmul) p *= postmul[d];
    pooled[nh * 64 + d] = p;
}

// ---------------------------------------------------------------------------
// ws byte offsets (~134 MB total)
// ---------------------------------------------------------------------------
#define OFF_BQH   0ull
#define OFF_BQL   524288ull
#define OFF_BKH   1048576ull
#define OFF_BKL   1572864ull
#define OFF_BVH   2097152ull
#define OFF_BVL   2621440ull
#define OFF_WBH   3145728ull
#define OFF_WBL   4194304ull
#define OFF_CVEC  5242880ull
#define OFF_GQ    5259264ull
#define OFF_PK    5292032ull
#define OFF_PART  5324800ull       // 128*16*65*4 = 532480 B
#define OFF_QBUF  8388608ull       // 64MB fp32 q
#define OFF_KV    75497472ull      // 64MB fp32 k then v

extern "C" void kernel_launch(void* const* d_in, const int* in_sizes, int n_in,
                              void* d_out, int out_size, void* d_ws, size_t ws_size,
                              hipStream_t stream) {
    const float* x_q  = (const float*)d_in[0];
    const float* x_kv = (const float*)d_in[1];
    const float* Wq   = (const float*)d_in[2];
    const float* bq   = (const float*)d_in[3];
    const float* wqa  = (const float*)d_in[4];
    const float* bqa  = (const float*)d_in[5];
    const float* Wk   = (const float*)d_in[6];
    const float* bk   = (const float*)d_in[7];
    const float* wka  = (const float*)d_in[8];
    const float* bka  = (const float*)d_in[9];
    const float* Wv   = (const float*)d_in[10];
    const float* bv   = (const float*)d_in[11];
    const float* Wt   = (const float*)d_in[12];
    const float* bt   = (const float*)d_in[13];
    const float* Wp   = (const float*)d_in[14];
    const float* bp   = (const float*)d_in[15];
    float* out = (float*)d_out;
    char* ws = (char*)d_ws;

    unsigned short* Bqh = (unsigned short*)(ws + OFF_BQH);
    unsigned short* Bql = (unsigned short*)(ws + OFF_BQL);
    unsigned short* Bkh = (unsigned short*)(ws + OFF_BKH);
    unsigned short* Bkl = (unsigned short*)(ws + OFF_BKL);
    unsigned short* Bvh = (unsigned short*)(ws + OFF_BVH);
    unsigned short* Bvl = (unsigned short*)(ws + OFF_BVL);
    unsigned short* WBh = (unsigned short*)(ws + OFF_WBH);
    unsigned short* WBl = (unsigned short*)(ws + OFF_WBL);
    float* cvec = (float*)(ws + OFF_CVEC);
    float* gq   = (float*)(ws + OFF_GQ);
    float* pk   = (float*)(ws + OFF_PK);
    float* part = (float*)(ws + OFF_PART);
    float* qbuf  = (float*)(ws + OFF_QBUF);
    float* kvbuf = (float*)(ws + OFF_KV);

    const dim3 pgrid(NB * HH, 16);

    // 1. weight prep (packed hi/lo + Wt-fold + cvec)
    prep_kernel<<<2048, 256, 0, stream>>>(Wq, Wk, Wv, Wt, bt, Wp, bp,
                                          Bqh, Bql, Bkh, Bkl, Bvh, Bvl, WBh, WBl, cvec);
    // 2. q projection
    gemm_f32a<16, 0, false><<<512, 512, 0, stream>>>(x_q, nullptr, nullptr, Bqh, Bql, bq, qbuf);
    // 3. q pooling -> gq = pooled_q * wka
    pool_stage1<<<pgrid, 256, 0, stream>>>(qbuf, wqa, bqa, part, 0);
    pool_stage2<<<NB * HH, 64, 0, stream>>>(part, wka, gq);
    // 4. k projection
    gemm_f32a<16, 0, false><<<512, 512, 0, stream>>>(x_kv, nullptr, nullptr, Bkh, Bkl, bk, kvbuf);
    // 5. k pooling -> pooled_k [16][512]
    pool_stage1<<<pgrid, 256, 0, stream>>>(kvbuf, gq, bka, part, 1);
    pool_stage2<<<NB * HH, 64, 0, stream>>>(part, nullptr, pk);
    // 6. v projection (k dead after pooling; overwrite kvbuf with v)
    gemm_f32a<16, 0, false><<<512, 512, 0, stream>>>(x_kv, nullptr, nullptr, Bvh, Bvl, bv, kvbuf);
    // 7. fused final: (v*pk)@Wbig + q@WpT + cvec  (gate applied in A1 staging)
    gemm_f32a<16, 16, true><<<512, 512, 0, stream>>>(kvbuf, qbuf, pk, WBh, WBl, cvec, out);
}

// Round 7
// 487.408 us; speedup vs baseline: 3.8246x; 1.0613x over previous
//
#include <hip/hip_runtime.h>
#include <hip/hip_bf16.h>
#include <math.h>

// Problem constants
#define NB 16
#define LL 2048
#define CC 512
#define HH 8
#define MM (NB*LL)          // 32768

typedef __attribute__((ext_vector_type(8))) short bf16x8;
typedef __attribute__((ext_vector_type(4))) float f32x4;
typedef __attribute__((ext_vector_type(8))) unsigned short u16x8;

// ---------------------------------------------------------------------------
// bf16 split helpers: x ≈ hi + lo, both bf16. Missing term lo*lo ~ 2^-18 rel.
// ---------------------------------------------------------------------------
__device__ inline unsigned short f2bf(float x) {
    __hip_bfloat16 b = __float2bfloat16(x);
    return __builtin_bit_cast(unsigned short, b);
}
__device__ inline float bf2f(unsigned short u) {
    __hip_bfloat16 b = __builtin_bit_cast(__hip_bfloat16, u);
    return __bfloat162float(b);
}
__device__ inline void split2(float x, unsigned short& h, unsigned short& l) {
    unsigned short hh = f2bf(x);
    float fh = bf2f(hh);
    h = hh;
    l = f2bf(x - fh);
}

// ---------------------------------------------------------------------------
// Prep: pack Wq/Wk/Wv hi/lo as [k>>3][c 0..511][k&7]; WpT packed the same for
// virtual k 512..1023; Wbig (Wt folded into Wp) kept fp32 in the SAME panel
// layout for later per-sample gating; cvec = bp + (bt broadcast) @ Wp^T.
// ---------------------------------------------------------------------------
__global__ __launch_bounds__(256)
void prep_kernel(const float* __restrict__ Wq, const float* __restrict__ Wk,
                 const float* __restrict__ Wv, const float* __restrict__ Wt,
                 const float* __restrict__ bt, const float* __restrict__ Wp,
                 const float* __restrict__ bp,
                 unsigned short* __restrict__ Bqh, unsigned short* __restrict__ Bql,
                 unsigned short* __restrict__ Bkh, unsigned short* __restrict__ Bkl,
                 unsigned short* __restrict__ Bvh, unsigned short* __restrict__ Bvl,
                 unsigned short* __restrict__ WPTh, unsigned short* __restrict__ WPTl,
                 float* __restrict__ WBFP, float* __restrict__ cvec)
{
    const int t = blockIdx.x * 256 + threadIdx.x;   // 512*1024 threads
    const int c = t >> 10;         // output col n, 0..511
    const int k = t & 1023;        // virtual K, 0..1023
    unsigned short hh, ll;
    if (k < 512) {   // Wbig[k=h*64+d][c] = sum_e Wt[e][d] * Wp[c][h*64+e]
        const int h = k >> 6, d = k & 63;
        float s = 0.f;
        #pragma unroll 8
        for (int e = 0; e < 64; ++e) s += Wt[e * 64 + d] * Wp[c * CC + h * 64 + e];
        const size_t pq = (((size_t)(k >> 3) * 512) + c) * 8 + (k & 7);
        WBFP[pq] = s;          // fp32, gated per-sample later
        split2(Wq[c * CC + k], hh, ll); Bqh[pq] = hh; Bql[pq] = ll;
        split2(Wk[c * CC + k], hh, ll); Bkh[pq] = hh; Bkl[pq] = ll;
        split2(Wv[c * CC + k], hh, ll); Bvh[pq] = hh; Bvl[pq] = ll;
    } else {
        const int kl = k - 512;
        const size_t pw = (((size_t)(kl >> 3) * 512) + c) * 8 + (kl & 7);
        split2(Wp[c * CC + kl], hh, ll);
        WPTh[pw] = hh; WPTl[pw] = ll;
    }
    if (k == 0) {
        float cv = bp[c];
        for (int j = 0; j < 512; ++j) cv += bt[j & 63] * Wp[c * CC + j];
        cvec[c] = cv;
    }
}

// ---------------------------------------------------------------------------
// Per-sample B-gate: WBG[smp] = diag(pk[smp]) * Wbig, split hi/lo, packed
// [kp][c][kc]. Folds the v-gate into the final GEMM's B operand.
// ---------------------------------------------------------------------------
__global__ __launch_bounds__(256)
void gate_wb(const float* __restrict__ WBFP, const float* __restrict__ pk,
             unsigned short* __restrict__ WBGh, unsigned short* __restrict__ WBGl)
{
    const int u = blockIdx.x * 256 + threadIdx.x;   // 524288
    const int smp = u >> 15;
    const int r = u & 32767;
    const int kp = r >> 9, c = r & 511;
    const float* w = &WBFP[(((size_t)kp * 512) + c) * 8];
    const float* p = &pk[smp * 512 + kp * 8];
    u16x8 hv, lv;
    #pragma unroll
    for (int j = 0; j < 8; ++j) {
        unsigned short h, lo;
        split2(w[j] * p[j], h, lo);
        hv[j] = h; lv[j] = lo;
    }
    const size_t o = (((size_t)smp * 64 + kp) * 512 + c) * 8;
    *(u16x8*)&WBGh[o] = hv;
    *(u16x8*)&WBGl[o] = lv;
}

// ---------------------------------------------------------------------------
// Projection GEMM: fp32 A staged+split in-kernel, packed hi/lo bf16 OUTPUT in
// [c>>3][m][c&7] layout (final-GEMM A layout) via LDS-bounce epilogue.
// BM=128, BN=256, BK=32, 512 thr = 8 waves (2M x 4N). K=512 (16 ktiles).
// Virtual nt: type = ntv>>1 selects {slot0, slot1} of A/B/bias/out pointers.
// ---------------------------------------------------------------------------
__global__ __launch_bounds__(512, 4)
void gemm_proj(const float* __restrict__ A0, const float* __restrict__ A1,
               const unsigned short* __restrict__ B0h, const unsigned short* __restrict__ B0l,
               const unsigned short* __restrict__ B1h, const unsigned short* __restrict__ B1l,
               const float* __restrict__ bias0, const float* __restrict__ bias1,
               unsigned short* __restrict__ O0h, unsigned short* __restrict__ O0l,
               unsigned short* __restrict__ O1h, unsigned short* __restrict__ O1l,
               int ntl)
{
    __shared__ __align__(16) unsigned short smem[24576];   // 48KB
    unsigned short* sAh = smem;
    unsigned short* sAl = smem + 4096;
    unsigned short* sBh = smem + 8192;
    unsigned short* sBl = smem + 16384;

    const int tid = threadIdx.x;
    const int flat = blockIdx.x;
    const int xcd = flat & 7, idx = flat >> 3;
    const int mt = xcd * 32 + (idx >> ntl);
    const int ntv = idx & ((1 << ntl) - 1);
    const int type = ntv >> 1;
    const int n0 = (ntv & 1) * 256;
    const int m0 = mt * 128;
    const int l = tid & 63, w = tid >> 6;
    const int wm = w >> 2, wn = w & 3;

    const float* Asrc = type ? A1 : A0;
    const unsigned short* Bh = type ? B1h : B0h;
    const unsigned short* Bl = type ? B1l : B0l;
    const float* bias = type ? bias1 : bias0;
    unsigned short* Oh = type ? O1h : O0h;
    unsigned short* Ol = type ? O1l : O0l;

    const int arow = tid & 127, akp = tid >> 7;     // A: 4 kp x 128 rows
    const int bcol = tid & 255, bkp0 = tid >> 8;    // B: slots (bkp0, bkp0+2)

    f32x4 acc[4][4] = {};

    float4 pa0, pa1;
    uint4 pbh0, pbh1, pbl0, pbl1;

    auto loadTile = [&](int kt) {
        const int k0 = kt * 32;
        const float* p = Asrc + (size_t)(m0 + arow) * CC + k0 + akp * 8;
        pa0 = *(const float4*)p; pa1 = *(const float4*)(p + 4);
        const int kpg = kt * 4;
        const size_t ob0 = (((size_t)(kpg + bkp0) * 512) + n0 + bcol) * 8;
        const size_t ob1 = (((size_t)(kpg + bkp0 + 2) * 512) + n0 + bcol) * 8;
        pbh0 = *(const uint4*)&Bh[ob0]; pbh1 = *(const uint4*)&Bh[ob1];
        pbl0 = *(const uint4*)&Bl[ob0]; pbl1 = *(const uint4*)&Bl[ob1];
    };

    auto storeTile = [&]() {
        float x[8];
        *(float4*)&x[0] = pa0; *(float4*)&x[4] = pa1;
        u16x8 hv, lv;
        #pragma unroll
        for (int j = 0; j < 8; ++j) { unsigned short h, lo; split2(x[j], h, lo); hv[j] = h; lv[j] = lo; }
        *(u16x8*)&sAh[(akp * 128 + arow) * 8] = hv;
        *(u16x8*)&sAl[(akp * 128 + arow) * 8] = lv;
        *(uint4*)&sBh[(bkp0 * 256 + bcol) * 8] = pbh0;
        *(uint4*)&sBh[((bkp0 + 2) * 256 + bcol) * 8] = pbh1;
        *(uint4*)&sBl[(bkp0 * 256 + bcol) * 8] = pbl0;
        *(uint4*)&sBl[((bkp0 + 2) * 256 + bcol) * 8] = pbl1;
    };

    loadTile(0);

    for (int kt = 0; kt < 16; ++kt) {
        __syncthreads();
        storeTile();
        __syncthreads();
        if (kt + 1 < 16) loadTile(kt + 1);

        const int g = l >> 4;
        const int rA = wm * 64 + (l & 15);
        const int rB = wn * 64 + (l & 15);
        const bf16x8* vAh = (const bf16x8*)sAh; const bf16x8* vAl = (const bf16x8*)sAl;
        const bf16x8* vBh = (const bf16x8*)sBh; const bf16x8* vBl = (const bf16x8*)sBl;
        bf16x8 ah[4], al[4], bh[4], bl[4];
        #pragma unroll
        for (int f = 0; f < 4; ++f) {
            ah[f] = vAh[g * 128 + rA + f * 16];
            al[f] = vAl[g * 128 + rA + f * 16];
            bh[f] = vBh[g * 256 + rB + f * 16];
            bl[f] = vBl[g * 256 + rB + f * 16];
        }
        #pragma unroll
        for (int i = 0; i < 4; ++i)
            #pragma unroll
            for (int j = 0; j < 4; ++j) {
                acc[i][j] = __builtin_amdgcn_mfma_f32_16x16x32_bf16(ah[i], bh[j], acc[i][j], 0, 0, 0);
                acc[i][j] = __builtin_amdgcn_mfma_f32_16x16x32_bf16(ah[i], bl[j], acc[i][j], 0, 0, 0);
                acc[i][j] = __builtin_amdgcn_mfma_f32_16x16x32_bf16(al[i], bh[j], acc[i][j], 0, 0, 0);
            }
    }

    // Packed epilogue via LDS bounce. C/D frag: col = lane&15, row = (l>>4)*4+e.
    // LDS [128][132] shorts (pad +4 => write conflict-free, read 2-way max).
    const int rowb = (l >> 4) * 4, colb = l & 15;
    const int hw = wn >> 1;            // which half this wave owns
    const int clbase = (wn & 1) * 64;
    unsigned short* sP = smem;
    for (int half = 0; half < 2; ++half) {
        for (int part = 0; part < 2; ++part) {
            __syncthreads();
            if (hw == half) {
                #pragma unroll
                for (int j = 0; j < 4; ++j) {
                    const float bv = bias[n0 + half * 128 + clbase + j * 16 + colb];
                    #pragma unroll
                    for (int i = 0; i < 4; ++i) {
                        #pragma unroll
                        for (int e = 0; e < 4; ++e) {
                            const int row = wm * 64 + i * 16 + rowb + e;
                            const int cl = clbase + j * 16 + colb;
                            unsigned short h, lo;
                            split2(acc[i][j][e] + bv, h, lo);
                            sP[row * 132 + cl] = part ? lo : h;
                        }
                    }
                }
            }
            __syncthreads();
            unsigned short* OP = part ? Ol : Oh;
            #pragma unroll
            for (int pass = 0; pass < 4; ++pass) {
                const int o = pass * 4 + (tid >> 7);
                const int row = tid & 127;
                const uint2 v0 = *(const uint2*)&sP[row * 132 + o * 8];
                const uint2 v1 = *(const uint2*)&sP[row * 132 + o * 8 + 4];
                const int cg = n0 + half * 128 + o * 8;
                uint4 val; val.x = v0.x; val.y = v0.y; val.z = v1.x; val.w = v1.y;
                *(uint4*)&OP[((size_t)(cg >> 3) * MM + m0 + row) * 8] = val;
            }
        }
    }
}

// ---------------------------------------------------------------------------
// Final GEMM: pure packed bf16 A (VP then QP), B = per-sample WBG then WPT.
// Same tile/wave structure; fp32 out + cvec. No gates, no splits.
// ---------------------------------------------------------------------------
__global__ __launch_bounds__(512, 4)
void gemm_final(const unsigned short* __restrict__ VPh, const unsigned short* __restrict__ VPl,
                const unsigned short* __restrict__ QPh, const unsigned short* __restrict__ QPl,
                const unsigned short* __restrict__ WBGh, const unsigned short* __restrict__ WBGl,
                const unsigned short* __restrict__ WPTh, const unsigned short* __restrict__ WPTl,
                const float* __restrict__ cvec, float* __restrict__ out)
{
    __shared__ __align__(16) unsigned short smem[24576];
    unsigned short* sAh = smem;
    unsigned short* sAl = smem + 4096;
    unsigned short* sBh = smem + 8192;
    unsigned short* sBl = smem + 16384;

    const int tid = threadIdx.x;
    const int flat = blockIdx.x;              // 512 blocks
    const int xcd = flat & 7, idx = flat >> 3;
    const int mt = xcd * 32 + (idx >> 1);
    const int nt = idx & 1;
    const int n0 = nt * 256, m0 = mt * 128;
    const int l = tid & 63, w = tid >> 6;
    const int wm = w >> 2, wn = w & 3;
    const int smp = mt >> 4;

    const int arow = tid & 127, akp = tid >> 7;
    const int bcol = tid & 255, bkp0 = tid >> 8;

    f32x4 acc[4][4] = {};

    uint4 pah, pal, pbh0, pbh1, pbl0, pbl1;

    auto loadTile = [&](int kt) {
        const int ktl = kt & 15;
        const unsigned short* Ah_ = (kt < 16) ? VPh : QPh;
        const unsigned short* Al_ = (kt < 16) ? VPl : QPl;
        const size_t ao = (((size_t)ktl * 4 + akp) * MM + m0 + arow) * 8;
        pah = *(const uint4*)&Ah_[ao];
        pal = *(const uint4*)&Al_[ao];
        const unsigned short* Bh_;
        const unsigned short* Bl_;
        size_t bb;
        if (kt < 16) { Bh_ = WBGh + (size_t)smp * 262144; Bl_ = WBGl + (size_t)smp * 262144; bb = kt * 4; }
        else         { Bh_ = WPTh; Bl_ = WPTl; bb = (kt - 16) * 4; }
        const size_t ob0 = ((bb + bkp0) * 512 + n0 + bcol) * 8;
        const size_t ob1 = ((bb + bkp0 + 2) * 512 + n0 + bcol) * 8;
        pbh0 = *(const uint4*)&Bh_[ob0]; pbh1 = *(const uint4*)&Bh_[ob1];
        pbl0 = *(const uint4*)&Bl_[ob0]; pbl1 = *(const uint4*)&Bl_[ob1];
    };

    auto storeTile = [&]() {
        *(uint4*)&sAh[(akp * 128 + arow) * 8] = pah;
        *(uint4*)&sAl[(akp * 128 + arow) * 8] = pal;
        *(uint4*)&sBh[(bkp0 * 256 + bcol) * 8] = pbh0;
        *(uint4*)&sBh[((bkp0 + 2) * 256 + bcol) * 8] = pbh1;
        *(uint4*)&sBl[(bkp0 * 256 + bcol) * 8] = pbl0;
        *(uint4*)&sBl[((bkp0 + 2) * 256 + bcol) * 8] = pbl1;
    };

    loadTile(0);

    for (int kt = 0; kt < 32; ++kt) {
        __syncthreads();
        storeTile();
        __syncthreads();
        if (kt + 1 < 32) loadTile(kt + 1);

        const int g = l >> 4;
        const int rA = wm * 64 + (l & 15);
        const int rB = wn * 64 + (l & 15);
        const bf16x8* vAh = (const bf16x8*)sAh; const bf16x8* vAl = (const bf16x8*)sAl;
        const bf16x8* vBh = (const bf16x8*)sBh; const bf16x8* vBl = (const bf16x8*)sBl;
        bf16x8 ah[4], al[4], bh[4], bl[4];
        #pragma unroll
        for (int f = 0; f < 4; ++f) {
            ah[f] = vAh[g * 128 + rA + f * 16];
            al[f] = vAl[g * 128 + rA + f * 16];
            bh[f] = vBh[g * 256 + rB + f * 16];
            bl[f] = vBl[g * 256 + rB + f * 16];
        }
        #pragma unroll
        for (int i = 0; i < 4; ++i)
            #pragma unroll
            for (int j = 0; j < 4; ++j) {
                acc[i][j] = __builtin_amdgcn_mfma_f32_16x16x32_bf16(ah[i], bh[j], acc[i][j], 0, 0, 0);
                acc[i][j] = __builtin_amdgcn_mfma_f32_16x16x32_bf16(ah[i], bl[j], acc[i][j], 0, 0, 0);
                acc[i][j] = __builtin_amdgcn_mfma_f32_16x16x32_bf16(al[i], bh[j], acc[i][j], 0, 0, 0);
            }
    }

    // epilogue: C/D layout col = lane&15, row = (lane>>4)*4 + reg  [m89/m91]
    const int rowb = (l >> 4) * 4, colb = l & 15;
    #pragma unroll
    for (int j = 0; j < 4; ++j) {
        const int c = n0 + wn * 64 + j * 16 + colb;
        const float bv = cvec[c];
        #pragma unroll
        for (int i = 0; i < 4; ++i) {
            const int r = m0 + wm * 64 + i * 16 + rowb;
            #pragma unroll
            for (int e = 0; e < 4; ++e)
                out[(size_t)(r + e) * CC + c] = acc[i][j][e] + bv;
        }
    }
}

// ---------------------------------------------------------------------------
// Pooling over packed hi/lo inputs: stage1 (scores+exp+weighted partials),
// stage2 (combine + divide). No max-sub needed (scores bounded).
// ---------------------------------------------------------------------------
__global__ __launch_bounds__(256)
void pool_stage1(const unsigned short* __restrict__ Ph, const unsigned short* __restrict__ Pl,
                 const float* __restrict__ wvec, const float* __restrict__ bscal,
                 float* __restrict__ partials, int modeK)
{
    __shared__ float sm[256];
    __shared__ float se[4];
    const int nh = blockIdx.x, chunk = blockIdx.y;
    const int n = nh >> 3, h = nh & 7;
    const int tid = threadIdx.x;
    const int wave = tid >> 6, d = tid & 63;
    const float wv = modeK ? wvec[nh * 64 + d] : wvec[d];
    const float b = bscal[0];
    const size_t rbase = ((size_t)(h * 8 + (d >> 3))) * MM + (size_t)n * LL;
    const int kc = d & 7;
    float accv = 0.f, acce = 0.f;
    const int l0 = chunk * 128 + wave;
    #pragma unroll 4
    for (int it = 0; it < 32; ++it) {
        const int ll = l0 + it * 4;
        const size_t a = (rbase + ll) * 8 + kc;
        const float x = bf2f(Ph[a]) + bf2f(Pl[a]);
        float s = x * wv;
        s += __shfl_xor(s, 1, 64);
        s += __shfl_xor(s, 2, 64);
        s += __shfl_xor(s, 4, 64);
        s += __shfl_xor(s, 8, 64);
        s += __shfl_xor(s, 16, 64);
        s += __shfl_xor(s, 32, 64);
        const float e = expf((s + b) * 0.125f);
        accv += e * x;
        acce += e;
    }
    sm[tid] = accv;
    if (d == 0) se[wave] = acce;
    __syncthreads();
    if (wave == 0) {
        const float pv = sm[d] + sm[64 + d] + sm[128 + d] + sm[192 + d];
        float* pr = partials + ((size_t)nh * 16 + chunk) * 65;
        pr[d] = pv;
        if (d == 0) pr[64] = se[0] + se[1] + se[2] + se[3];
    }
}

__global__ __launch_bounds__(64)
void pool_stage2(const float* __restrict__ partials, const float* __restrict__ postmul,
                 float* __restrict__ pooled)
{
    const int nh = blockIdx.x, d = threadIdx.x;
    float pv = 0.f, pe = 0.f;
    #pragma unroll
    for (int c = 0; c < 16; ++c) {
        const float* pr = partials + ((size_t)nh * 16 + c) * 65;
        pv += pr[d];
        pe += pr[64];
    }
    float p = pv / pe;
    if (postmul) p *= postmul[d];
    pooled[nh * 64 + d] = p;
}

// ---------------------------------------------------------------------------
// ws byte offsets (~150 MB total)
// ---------------------------------------------------------------------------
#define OFF_BQH   0ull
#define OFF_BQL   524288ull
#define OFF_BKH   1048576ull
#define OFF_BKL   1572864ull
#define OFF_BVH   2097152ull
#define OFF_BVL   2621440ull
#define OFF_WPTH  3145728ull
#define OFF_WPTL  3670016ull
#define OFF_WBFP  4194304ull       // 1MB fp32 Wbig (panel layout)
#define OFF_CVEC  5242880ull
#define OFF_GQ    5246976ull
#define OFF_PK    5279744ull
#define OFF_PART  5312512ull       // 532480 B
#define OFF_WBGH  6291456ull       // 8MB per-sample gated Wbig hi
#define OFF_WBGL  14680064ull      // 8MB lo
#define OFF_QPH   23068672ull      // 32MB
#define OFF_QPL   56623104ull      // 32MB
#define OFF_KPH   90177536ull      // 32MB (k, then v aliases)
#define OFF_KPL   123731968ull     // 32MB

extern "C" void kernel_launch(void* const* d_in, const int* in_sizes, int n_in,
                              void* d_out, int out_size, void* d_ws, size_t ws_size,
                              hipStream_t stream) {
    const float* x_q  = (const float*)d_in[0];
    const float* x_kv = (const float*)d_in[1];
    const float* Wq   = (const float*)d_in[2];
    const float* bq   = (const float*)d_in[3];
    const float* wqa  = (const float*)d_in[4];
    const float* bqa  = (const float*)d_in[5];
    const float* Wk   = (const float*)d_in[6];
    const float* bk   = (const float*)d_in[7];
    const float* wka  = (const float*)d_in[8];
    const float* bka  = (const float*)d_in[9];
    const float* Wv   = (const float*)d_in[10];
    const float* bv   = (const float*)d_in[11];
    const float* Wt   = (const float*)d_in[12];
    const float* bt   = (const float*)d_in[13];
    const float* Wp   = (const float*)d_in[14];
    const float* bp   = (const float*)d_in[15];
    float* out = (float*)d_out;
    char* ws = (char*)d_ws;

    unsigned short* Bqh  = (unsigned short*)(ws + OFF_BQH);
    unsigned short* Bql  = (unsigned short*)(ws + OFF_BQL);
    unsigned short* Bkh  = (unsigned short*)(ws + OFF_BKH);
    unsigned short* Bkl  = (unsigned short*)(ws + OFF_BKL);
    unsigned short* Bvh  = (unsigned short*)(ws + OFF_BVH);
    unsigned short* Bvl  = (unsigned short*)(ws + OFF_BVL);
    unsigned short* WPTh = (unsigned short*)(ws + OFF_WPTH);
    unsigned short* WPTl = (unsigned short*)(ws + OFF_WPTL);
    float* WBFP = (float*)(ws + OFF_WBFP);
    float* cvec = (float*)(ws + OFF_CVEC);
    float* gq   = (float*)(ws + OFF_GQ);
    float* pk   = (float*)(ws + OFF_PK);
    float* part = (float*)(ws + OFF_PART);
    unsigned short* WBGh = (unsigned short*)(ws + OFF_WBGH);
    unsigned short* WBGl = (unsigned short*)(ws + OFF_WBGL);
    unsigned short* QPh  = (unsigned short*)(ws + OFF_QPH);
    unsigned short* QPl  = (unsigned short*)(ws + OFF_QPL);
    unsigned short* KPh  = (unsigned short*)(ws + OFF_KPH);   // k, then v
    unsigned short* KPl  = (unsigned short*)(ws + OFF_KPL);

    const dim3 pgrid(NB * HH, 16);

    // 1. weight prep
    prep_kernel<<<2048, 256, 0, stream>>>(Wq, Wk, Wv, Wt, bt, Wp, bp,
                                          Bqh, Bql, Bkh, Bkl, Bvh, Bvl,
                                          WPTh, WPTl, WBFP, cvec);
    // 2. fused Q+K projections (packed hi/lo outputs)
    gemm_proj<<<1024, 512, 0, stream>>>(x_q, x_kv, Bqh, Bql, Bkh, Bkl, bq, bk,
                                        QPh, QPl, KPh, KPl, 2);
    // 3. q pooling -> gq = pooled_q * wka
    pool_stage1<<<pgrid, 256, 0, stream>>>(QPh, QPl, wqa, bqa, part, 0);
    pool_stage2<<<NB * HH, 64, 0, stream>>>(part, wka, gq);
    // 4. k pooling -> pooled_k [16][512]
    pool_stage1<<<pgrid, 256, 0, stream>>>(KPh, KPl, gq, bka, part, 1);
    pool_stage2<<<NB * HH, 64, 0, stream>>>(part, nullptr, pk);
    // 5. fold gate into B: WBG[smp] = diag(pk) * Wbig, split+packed
    gate_wb<<<2048, 256, 0, stream>>>(WBFP, pk, WBGh, WBGl);
    // 6. v projection (ungated; overwrites k's packed buffers)
    gemm_proj<<<512, 512, 0, stream>>>(x_kv, x_kv, Bvh, Bvl, Bvh, Bvl, bv, bv,
                                       KPh, KPl, KPh, KPl, 1);
    // 7. final: v@WBG[smp] + q@WpT + cvec
    gemm_final<<<512, 512, 0, stream>>>(KPh, KPl, QPh, QPl, WBGh, WBGl,
                                        WPTh, WPTl, cvec, out);
}